// Round 2
// baseline (450.060 us; speedup 1.0000x reference)
//
#include <hip/hip_runtime.h>
#include <hip/hip_bf16.h>

typedef unsigned short u16;
typedef __attribute__((ext_vector_type(8))) short short8;
typedef __attribute__((ext_vector_type(4))) float f32x4;

#define NELEM 524288          // 8*64*32*32
#define PADW 34
#define PLANE 73984           // 34*34*64 elements per padded image
#define SEQ 32

__device__ inline void split3(float v, u16& a, u16& b, u16& c) {
  __hip_bfloat16 h1 = __float2bfloat16(v);
  float r1 = v - __bfloat162float(h1);
  __hip_bfloat16 h2 = __float2bfloat16(r1);
  float r2 = r1 - __bfloat162float(h2);
  __hip_bfloat16 h3 = __float2bfloat16(r2);
  a = *reinterpret_cast<u16*>(&h1);
  b = *reinterpret_cast<u16*>(&h2);
  c = *reinterpret_cast<u16*>(&h3);
}

__global__ void zero_kernel(uint4* __restrict__ p, int n) {
  int i = blockIdx.x * blockDim.x + threadIdx.x;
  int stride = gridDim.x * blockDim.x;
  uint4 z; z.x = 0u; z.y = 0u; z.z = 0u; z.w = 0u;
  for (; i < n; i += stride) p[i] = z;
}

// Constant-current LIF encoder in f64: x(t) for all t, written bf16 (exact 0/1),
// padded channel-last layout xp[t][b][y][x][c].
__global__ void encode_kernel(const float* __restrict__ input, u16* __restrict__ xp) {
  int e = blockIdx.x * 256 + threadIdx.x;   // ((b*1024)+hw)*64 + c
  int c = e & 63;
  int hw = (e >> 6) & 1023;
  int b = e >> 16;
  int h = hw >> 5, w = hw & 31;
  const double DMI = 0.001 * 100.0;
  double inp = (double)input[(size_t)(((b << 6) + c) << 10) + hw];
  size_t base = ((size_t)(b * PADW + h + 1) * PADW + (w + 1)) * 64 + c;
  double ve = 0.0;
  for (int t = 0; t < SEQ; ++t) {
    double v = ve + DMI * (inp - ve);
    bool x = v > 1.0;
    ve = x ? 0.0 : v;
    xp[(size_t)t * (8 * PLANE) + base] = x ? (u16)0x3F80 : (u16)0;
  }
}

// h0 / c0 -> padded channel-last, 3-way bf16 split
__global__ void prep_hc_kernel(const float* __restrict__ h0, const float* __restrict__ c0,
                               u16* __restrict__ h1, u16* __restrict__ h2, u16* __restrict__ h3,
                               u16* __restrict__ c1, u16* __restrict__ c2, u16* __restrict__ c3) {
  int e = blockIdx.x * 256 + threadIdx.x;
  int c = e & 63;
  int hw = (e >> 6) & 1023;
  int b = e >> 16;
  int h = hw >> 5, w = hw & 31;
  size_t src = (size_t)(((b << 6) + c) << 10) + hw;
  size_t dst = ((size_t)(b * PADW + h + 1) * PADW + (w + 1)) * 64 + c;
  u16 a, bb, cc;
  split3(h0[src], a, bb, cc); h1[dst] = a; h2[dst] = bb; h3[dst] = cc;
  split3(c0[src], a, bb, cc); c1[dst] = a; c2[dst] = bb; c3[dst] = cc;
}

// Pack live weight rows into [tap][M][64c] bf16 3-way split. o-gate rows are dead.
__global__ void prep_w_kernel(const float* __restrict__ wih, const float* __restrict__ whh,
                              const float* __restrict__ wch,
                              u16* __restrict__ ih1, u16* __restrict__ ih2, u16* __restrict__ ih3,
                              u16* __restrict__ hh1, u16* __restrict__ hh2, u16* __restrict__ hh3,
                              u16* __restrict__ ch1, u16* __restrict__ ch2, u16* __restrict__ ch3) {
  int t = blockIdx.x * 256 + threadIdx.x;   // (tap*512 + row)*64 + c ; 9*512*64 threads
  int c = t & 63;
  int row = (t >> 6) & 511;
  int tap = t >> 15;
  const float* src; u16 *d1, *d2, *d3; int m, Mtot;
  if (row < 192)      { src = wih; m = row;       Mtot = 192; d1 = ih1; d2 = ih2; d3 = ih3; }
  else if (row < 384) { src = whh; m = row - 192; Mtot = 192; d1 = hh1; d2 = hh2; d3 = hh3; }
  else                { src = wch; m = row - 384; Mtot = 128; d1 = ch1; d2 = ch2; d3 = ch3; }
  float v = src[(size_t)((m << 6) + c) * 9 + tap];
  u16 a, b, cc; split3(v, a, b, cc);
  size_t d = (size_t)(tap * Mtot + m) * 64 + c;
  d1[d] = a; d2[d] = b; d3[d] = cc;
}

// 3x3 conv as 9 shifted GEMMs over channel-last padded LDS tiles.
// Block: 256 thr = 4 waves. Tile: BM=64 (weights), BN=128 pixels (4 rows x 32).
// Wave (wm,wn): 32m x 64px -> 2x4 frags of 16x16x32 MFMA.
// Loop: taps outer (stage all 3 W parts once per tap), segments inner.
// MODE 0 (wx): 1 A-plane (exact 0/1 spikes) x 3 W parts.
// MODE 1 (wh/wc): 3 A-planes x 3 W parts, 6 significant cross products.
template<int MODE>
__global__ __launch_bounds__(256) void conv9_kernel(
    const u16* __restrict__ A0, const u16* __restrict__ A1, const u16* __restrict__ A2,
    const u16* __restrict__ W0, const u16* __restrict__ W1, const u16* __restrict__ W2,
    float* __restrict__ out, int Mtot) {
  constexpr int NPLANES = MODE ? 3 : 1;
  constexpr int NSEG = MODE ? 6 : 3;
  __shared__ uint4 ldsx4[NPLANES * 1632];   // per plane: 6 rows x 34 x 64ch bf16
  __shared__ uint4 ldsw4[3 * 512];          // per part: 64m x 64c bf16
  char* ldsx = (char*)ldsx4;
  char* ldsw = (char*)ldsw4;

  const int tid = threadIdx.x;
  const int lane = tid & 63;
  const int wid = tid >> 6;
  const int mtile = blockIdx.x;
  const int rg = blockIdx.y;
  const int img = blockIdx.z;

  {  // stage X planes (swizzled: byte ^= (pixel&7)<<4)
    const u16* aps[3] = {A0, A1, A2};
    size_t abase = (size_t)img * PLANE + (size_t)rg * 4 * (PADW * 64);
#pragma unroll
    for (int pl = 0; pl < NPLANES; ++pl) {
      const u16* src = aps[pl] + abase;
      for (int q = tid; q < 1632; q += 256) {
        int p = q >> 3, g = q & 7;
        uint4 v = *reinterpret_cast<const uint4*>(src + p * 64 + g * 8);
        int byte = (p * 128 + g * 16) ^ ((p & 7) << 4);
        *reinterpret_cast<uint4*>(ldsx + pl * 26112 + byte) = v;
      }
    }
  }

  f32x4 acc[2][4];
#pragma unroll
  for (int i = 0; i < 2; ++i)
#pragma unroll
    for (int j = 0; j < 4; ++j)
#pragma unroll
      for (int k = 0; k < 4; ++k) acc[i][j][k] = 0.f;

  const int wm = wid >> 1, wn = wid & 1;
  const u16* wps[3] = {W0, W1, W2};
  // segment tables: (A-plane index, W-part index)
  constexpr int segA0t[6] = {0, 0, 0, 0, 0, 0};
  constexpr int segW0t[6] = {0, 1, 2, 0, 0, 0};
  constexpr int segA1t[6] = {0, 0, 1, 1, 0, 2};
  constexpr int segW1t[6] = {0, 1, 0, 1, 2, 0};

  for (int tap = 0; tap < 9; ++tap) {
    __syncthreads();
    {  // stage 3 W part tiles for this tap (swizzled)
      size_t wrow0 = ((size_t)tap * Mtot + mtile * 64) * 64;
      for (int q = tid; q < 1536; q += 256) {
        int part = q >> 9, m = (q >> 3) & 63, g = q & 7;
        uint4 v = *reinterpret_cast<const uint4*>(wps[part] + wrow0 + m * 64 + g * 8);
        int byte = (m * 128 + g * 16) ^ ((m & 7) << 4);
        *reinterpret_cast<uint4*>(ldsw + part * 8192 + byte) = v;
      }
    }
    __syncthreads();
    const int kh = tap / 3, kw = tap - kh * 3;
#pragma unroll
    for (int s = 0; s < NSEG; ++s) {
      const int plofs = (MODE ? segA1t[s] : segA0t[s]) * 26112;
      const int wofs = (MODE ? segW1t[s] : segW0t[s]) * 8192;
#pragma unroll
      for (int khalf = 0; khalf < 2; ++khalf) {
        short8 af[2], bfr[4];
#pragma unroll
        for (int fm = 0; fm < 2; ++fm) {
          int m = wm * 32 + fm * 16 + (lane & 15);
          int byte = (m * 128 + khalf * 64 + (lane >> 4) * 16) ^ ((m & 7) << 4);
          af[fm] = *reinterpret_cast<const short8*>(ldsw + wofs + byte);
        }
#pragma unroll
        for (int fn = 0; fn < 4; ++fn) {
          int p = wn * 64 + fn * 16 + (lane & 15);
          int r = p >> 5, w = p & 31;
          int pL = (r + kh) * PADW + (w + kw);
          int byte = (pL * 128 + khalf * 64 + (lane >> 4) * 16) ^ ((pL & 7) << 4);
          bfr[fn] = *reinterpret_cast<const short8*>(ldsx + plofs + byte);
        }
#pragma unroll
        for (int fm = 0; fm < 2; ++fm)
#pragma unroll
          for (int fn = 0; fn < 4; ++fn)
            acc[fm][fn] = __builtin_amdgcn_mfma_f32_16x16x32_bf16(af[fm], bfr[fn], acc[fm][fn], 0, 0, 0);
      }
    }
  }

  // D layout: col=lane&15 (pixel), row=(lane>>4)*4+reg (m)
  size_t obase = (size_t)img * Mtot * 1024;
#pragma unroll
  for (int fm = 0; fm < 2; ++fm)
#pragma unroll
    for (int fn = 0; fn < 4; ++fn) {
      int pcol = rg * 128 + wn * 64 + fn * 16 + (lane & 15);
      int mrow0 = mtile * 64 + wm * 32 + fm * 16 + (lane >> 4) * 4;
#pragma unroll
      for (int r2 = 0; r2 < 4; ++r2)
        out[obase + (size_t)(mrow0 + r2) * 1024 + pcol] = acc[fm][fn][r2];
    }
}

// Sequential LIF gate scan over a chunk of timesteps. f64 states, f32 conv inputs.
__global__ void scan_kernel(const float* __restrict__ wx,   // [nt*8][192][1024]
                            const float* __restrict__ wh,   // [8][192][1024]
                            const float* __restrict__ wcb,  // [8][128][1024]
                            const float* __restrict__ bih, const float* __restrict__ bhh,
                            const float* __restrict__ bch,
                            double* __restrict__ st, int t0, int nt) {
  const double DMI = 0.001 * 100.0;   // dt * tau_mem_inv
  const double DSI = 0.001 * 200.0;   // dt * tau_syn_inv
  int e = blockIdx.x * 256 + threadIdx.x;   // ((b*64+c)*1024)+hw
  int hw = e & 1023;
  int c = (e >> 10) & 63;
  int b = e >> 16;
  size_t o0 = ((size_t)b * 192 + c) * 1024 + hw;
  size_t w0 = ((size_t)b * 128 + c) * 1024 + hw;
  double cI = ((double)wh[o0] + (double)bhh[c]) + ((double)wcb[w0] + (double)bch[c]);
  double cF = ((double)wh[o0 + 64 * 1024] + (double)bhh[64 + c]) +
              ((double)wcb[w0 + 64 * 1024] + (double)bch[64 + c]);
  double cG = (double)wh[o0 + 128 * 1024] + (double)bhh[128 + c];
  double bI = (double)bih[c], bF = (double)bih[64 + c], bG = (double)bih[128 + c];

  double vi, ii, vf, fi, vg, gi, mi, mf, mg, mo;
  if (t0 == 0) {
    vi = ii = vf = fi = vg = gi = 0.0;
    mi = mf = mg = mo = -INFINITY;
  } else {
    vi = st[0 * NELEM + e]; ii = st[1 * NELEM + e];
    vf = st[2 * NELEM + e]; fi = st[3 * NELEM + e];
    vg = st[4 * NELEM + e]; gi = st[5 * NELEM + e];
    mi = st[6 * NELEM + e]; mf = st[7 * NELEM + e];
    mg = st[8 * NELEM + e]; mo = st[9 * NELEM + e];
  }
  for (int t = 0; t < nt; ++t) {
    const float* wp = wx + (size_t)(t * 8 + b) * (192 * 1024);
    double inpI = ((double)wp[(size_t)c * 1024 + hw] + bI) + cI;
    double inpF = ((double)wp[(size_t)(64 + c) * 1024 + hw] + bF) + cF;
    double inpG = ((double)wp[(size_t)(128 + c) * 1024 + hw] + bG) + cG;
    // gate i (v_dec uses old current; current updated after)
    double vd = vi + DMI * (ii - vi);
    vi = (vd > 1.0) ? 0.0 : vd;
    ii = (ii - DSI * ii) + inpI;
    // gate f
    vd = vf + DMI * (fi - vf);
    vf = (vd > 1.0) ? 0.0 : vd;
    fi = (fi - DSI * fi) + inpF;
    // gate g
    vd = vg + DMI * (gi - vg);
    vg = (vd > 1.0) ? 0.0 : vd;
    gi = (gi - DSI * gi) + inpG;
    // gate o: reference feeds the JUST-updated g state; its input conv is dead
    double vod = vg + DMI * (gi - vg);
    double vo = (vod > 1.0) ? 0.0 : vod;
    if (t0 + t >= 1) {
      mi = fmax(mi, vi); mf = fmax(mf, vf);
      mg = fmax(mg, vg); mo = fmax(mo, vo);
    }
  }
  st[0 * NELEM + e] = vi; st[1 * NELEM + e] = ii;
  st[2 * NELEM + e] = vf; st[3 * NELEM + e] = fi;
  st[4 * NELEM + e] = vg; st[5 * NELEM + e] = gi;
  st[6 * NELEM + e] = mi; st[7 * NELEM + e] = mf;
  st[8 * NELEM + e] = mg; st[9 * NELEM + e] = mo;
}

__global__ void final_kernel(const double* __restrict__ st, const float* __restrict__ c0,
                             float* __restrict__ out) {
  int e = blockIdx.x * 256 + threadIdx.x;
  double mi = st[6 * NELEM + e], mf = st[7 * NELEM + e];
  double mg = st[8 * NELEM + e], mo = st[9 * NELEM + e];
  double c1 = mf * (double)c0[e] + mi * mg;
  out[e] = (float)(mo * tanh(c1));
  out[NELEM + e] = (float)c1;
}

extern "C" void kernel_launch(void* const* d_in, const int* in_sizes, int n_in,
                              void* d_out, int out_size, void* d_ws, size_t ws_size,
                              hipStream_t stream) {
  const float* input = (const float*)d_in[0];
  const float* h0    = (const float*)d_in[1];
  const float* c0    = (const float*)d_in[2];
  const float* wih   = (const float*)d_in[3];
  const float* whh   = (const float*)d_in[4];
  const float* wch   = (const float*)d_in[5];
  const float* bih   = (const float*)d_in[6];
  const float* bhh   = (const float*)d_in[7];
  const float* bch   = (const float*)d_in[8];
  char* ws = (char*)d_ws;

  size_t off = 0;
  auto take = [&](size_t bytes) { size_t o = off; off += (bytes + 255) & ~(size_t)255; return o; };
  size_t oXp  = take((size_t)SEQ * 8 * PLANE * 2);     // 37,879,808 (zeroed)
  size_t oH1  = take((size_t)8 * PLANE * 2);           // 6 planes, contiguous (zeroed)
  size_t oH2  = take((size_t)8 * PLANE * 2);
  size_t oH3  = take((size_t)8 * PLANE * 2);
  size_t oC1  = take((size_t)8 * PLANE * 2);
  size_t oC2  = take((size_t)8 * PLANE * 2);
  size_t oC3  = take((size_t)8 * PLANE * 2);
  size_t oIh1 = take((size_t)9 * 192 * 64 * 2);
  size_t oIh2 = take((size_t)9 * 192 * 64 * 2);
  size_t oIh3 = take((size_t)9 * 192 * 64 * 2);
  size_t oHh1 = take((size_t)9 * 192 * 64 * 2);
  size_t oHh2 = take((size_t)9 * 192 * 64 * 2);
  size_t oHh3 = take((size_t)9 * 192 * 64 * 2);
  size_t oCh1 = take((size_t)9 * 128 * 64 * 2);
  size_t oCh2 = take((size_t)9 * 128 * 64 * 2);
  size_t oCh3 = take((size_t)9 * 128 * 64 * 2);
  size_t oWh  = take((size_t)8 * 192 * 1024 * 4);
  size_t oWc  = take((size_t)8 * 128 * 1024 * 4);
  size_t oSt  = take((size_t)10 * NELEM * 8);
  size_t fixedEnd = off;
  const size_t chunkBytes = (size_t)8 * 192 * 1024 * 4;  // per-timestep wx bytes
  int chunk = 32;
  while (chunk > 1 && fixedEnd + (size_t)chunk * chunkBytes > ws_size) chunk >>= 1;
  size_t oWx = fixedEnd;

  u16* xp  = (u16*)(ws + oXp);
  u16* h1p = (u16*)(ws + oH1); u16* h2p = (u16*)(ws + oH2); u16* h3p = (u16*)(ws + oH3);
  u16* c1p = (u16*)(ws + oC1); u16* c2p = (u16*)(ws + oC2); u16* c3p = (u16*)(ws + oC3);
  u16* ih1 = (u16*)(ws + oIh1); u16* ih2 = (u16*)(ws + oIh2); u16* ih3 = (u16*)(ws + oIh3);
  u16* hh1 = (u16*)(ws + oHh1); u16* hh2 = (u16*)(ws + oHh2); u16* hh3 = (u16*)(ws + oHh3);
  u16* ch1 = (u16*)(ws + oCh1); u16* ch2 = (u16*)(ws + oCh2); u16* ch3 = (u16*)(ws + oCh3);
  float* whb = (float*)(ws + oWh);
  float* wcb = (float*)(ws + oWc);
  double* st = (double*)(ws + oSt);
  float* wxb = (float*)(ws + oWx);

  // zero the padded-plane region (Xp + 6 h/c planes are contiguous)
  int nZero = (int)(((size_t)SEQ * 8 * PLANE * 2 + 6 * ((size_t)8 * PLANE * 2)) / 16);
  zero_kernel<<<2048, 256, 0, stream>>>((uint4*)(ws + oXp), nZero);
  encode_kernel<<<2048, 256, 0, stream>>>(input, xp);
  prep_hc_kernel<<<2048, 256, 0, stream>>>(h0, c0, h1p, h2p, h3p, c1p, c2p, c3p);
  prep_w_kernel<<<1152, 256, 0, stream>>>(wih, whh, wch, ih1, ih2, ih3,
                                          hh1, hh2, hh3, ch1, ch2, ch3);

  conv9_kernel<1><<<dim3(3, 8, 8), 256, 0, stream>>>(h1p, h2p, h3p, hh1, hh2, hh3, whb, 192);
  conv9_kernel<1><<<dim3(2, 8, 8), 256, 0, stream>>>(c1p, c2p, c3p, ch1, ch2, ch3, wcb, 128);

  for (int t0 = 0; t0 < SEQ; t0 += chunk) {
    conv9_kernel<0><<<dim3(3, 8, 8 * chunk), 256, 0, stream>>>(
        xp + (size_t)t0 * 8 * PLANE, nullptr, nullptr, ih1, ih2, ih3, wxb, 192);
    scan_kernel<<<2048, 256, 0, stream>>>(wxb, whb, wcb, bih, bhh, bch, st, t0, chunk);
  }
  final_kernel<<<2048, 256, 0, stream>>>(st, c0, (float*)d_out);
}

// Round 3
// 352.093 us; speedup vs baseline: 1.2782x; 1.2782x over previous
//
#include <hip/hip_runtime.h>
#include <hip/hip_bf16.h>
#include <hip/hip_fp16.h>

typedef unsigned short u16;
typedef __attribute__((ext_vector_type(8))) short short8;
typedef __attribute__((ext_vector_type(4))) float f32x4;

#define NELEM 524288          // 8*64*32*32
#define PADW 34
#define PLANE 73984           // 34*34*64 elements per padded image
#define SEQ 32

__device__ inline void split3(float v, u16& a, u16& b, u16& c) {
  __hip_bfloat16 h1 = __float2bfloat16(v);
  float r1 = v - __bfloat162float(h1);
  __hip_bfloat16 h2 = __float2bfloat16(r1);
  float r2 = r1 - __bfloat162float(h2);
  __hip_bfloat16 h3 = __float2bfloat16(r2);
  a = *reinterpret_cast<u16*>(&h1);
  b = *reinterpret_cast<u16*>(&h2);
  c = *reinterpret_cast<u16*>(&h3);
}

__device__ inline void gload16(const void* g, void* l) {
  typedef const __attribute__((address_space(1))) void* gp_t;
  typedef __attribute__((address_space(3))) void* lp_t;
  __builtin_amdgcn_global_load_lds((gp_t)g, (lp_t)l, 16, 0, 0);
}

__global__ void zero_kernel(uint4* __restrict__ p, int n) {
  int i = blockIdx.x * blockDim.x + threadIdx.x;
  int stride = gridDim.x * blockDim.x;
  uint4 z; z.x = 0u; z.y = 0u; z.z = 0u; z.w = 0u;
  for (; i < n; i += stride) p[i] = z;
}

// Constant-current LIF encoder in f64: x(t) for all t, written f16 (exact 0/1),
// padded channel-last layout xp[t][b][y][x][c].
__global__ void encode_kernel(const float* __restrict__ input, u16* __restrict__ xp) {
  int e = blockIdx.x * 256 + threadIdx.x;   // ((b*1024)+hw)*64 + c
  int c = e & 63;
  int hw = (e >> 6) & 1023;
  int b = e >> 16;
  int h = hw >> 5, w = hw & 31;
  const double DMI = 0.001 * 100.0;
  double inp = (double)input[(size_t)(((b << 6) + c) << 10) + hw];
  size_t base = ((size_t)(b * PADW + h + 1) * PADW + (w + 1)) * 64 + c;
  double ve = 0.0;
  for (int t = 0; t < SEQ; ++t) {
    double v = ve + DMI * (inp - ve);
    bool x = v > 1.0;
    ve = x ? 0.0 : v;
    xp[(size_t)t * (8 * PLANE) + base] = x ? (u16)0x3C00 : (u16)0;   // f16 1.0
  }
}

// h0 / c0 -> padded channel-last, 3-way bf16 split (unchanged, proven)
__global__ void prep_hc_kernel(const float* __restrict__ h0, const float* __restrict__ c0,
                               u16* __restrict__ h1, u16* __restrict__ h2, u16* __restrict__ h3,
                               u16* __restrict__ c1, u16* __restrict__ c2, u16* __restrict__ c3) {
  int e = blockIdx.x * 256 + threadIdx.x;
  int c = e & 63;
  int hw = (e >> 6) & 1023;
  int b = e >> 16;
  int h = hw >> 5, w = hw & 31;
  size_t src = (size_t)(((b << 6) + c) << 10) + hw;
  size_t dst = ((size_t)(b * PADW + h + 1) * PADW + (w + 1)) * 64 + c;
  u16 a, bb, cc;
  split3(h0[src], a, bb, cc); h1[dst] = a; h2[dst] = bb; h3[dst] = cc;
  split3(c0[src], a, bb, cc); c1[dst] = a; c2[dst] = bb; c3[dst] = cc;
}

// Weights: ih -> f16 2-part with power-of-2 pre-scale (avoids f16 denorm flush):
//   w1 = f16(w*2^9), w2 = f16((w*2^9 - w1)*2^12); w = w1*2^-9 + w2*2^-21 + O(5e-9)
// hh/ch -> bf16 3-part (unchanged). o-gate rows are dead.
__global__ void prep_w_kernel(const float* __restrict__ wih, const float* __restrict__ whh,
                              const float* __restrict__ wch,
                              u16* __restrict__ ih1, u16* __restrict__ ih2,
                              u16* __restrict__ hh1, u16* __restrict__ hh2, u16* __restrict__ hh3,
                              u16* __restrict__ ch1, u16* __restrict__ ch2, u16* __restrict__ ch3) {
  int t = blockIdx.x * 256 + threadIdx.x;   // (tap*512 + row)*64 + c
  int c = t & 63;
  int row = (t >> 6) & 511;
  int tap = t >> 15;
  if (row < 192) {
    float v = wih[(size_t)((row << 6) + c) * 9 + tap] * 512.0f;
    __half a = __float2half(v);
    float r = (v - __half2float(a)) * 4096.0f;
    __half b = __float2half(r);
    size_t d = (size_t)(tap * 192 + row) * 64 + c;
    ih1[d] = *reinterpret_cast<u16*>(&a);
    ih2[d] = *reinterpret_cast<u16*>(&b);
  } else {
    const float* src; u16 *d1, *d2, *d3; int m, Mtot;
    if (row < 384) { src = whh; m = row - 192; Mtot = 192; d1 = hh1; d2 = hh2; d3 = hh3; }
    else           { src = wch; m = row - 384; Mtot = 128; d1 = ch1; d2 = ch2; d3 = ch3; }
    float v = src[(size_t)((m << 6) + c) * 9 + tap];
    u16 a, b, cc; split3(v, a, b, cc);
    size_t d = (size_t)(tap * Mtot + m) * 64 + c;
    d1[d] = a; d2[d] = b; d3[d] = cc;
  }
}

// 3x3 conv as 9 shifted GEMMs over channel-last padded LDS tiles.
// Block: 256 thr = 4 waves. Tile: BM=64, BN=128 px (4 rows x 32). Wave: 32m x 64px.
// Schedule: "minimum 2-phase" — W(tap+1) prefetched via global_load_lds (pre-swizzled
// source, linear LDS dest) into double buffer BEFORE tap's compute; 1 barrier/tap.
// MODE 0 (wx): f16 spikes x 2 scaled f16 W parts -> dual accumulators.
// MODE 1 (wh/wc): bf16, 3 A-planes x 3 W parts, 6 cross terms, single accumulator.
template<int MODE>
__global__ __launch_bounds__(256) void conv9_kernel(
    const u16* __restrict__ A0, const u16* __restrict__ A1, const u16* __restrict__ A2,
    const u16* __restrict__ W0, const u16* __restrict__ W1, const u16* __restrict__ W2,
    float* __restrict__ out, int Mtot) {
  constexpr int NPLANES = MODE ? 3 : 1;
  constexpr int NPARTS  = MODE ? 3 : 2;
  constexpr int WBUF = NPARTS * 8192;
  __shared__ uint4 ldsx4[NPLANES * 1632];   // per plane: 6 rows x 34 x 64ch
  __shared__ uint4 ldsw4[2 * NPARTS * 512]; // dbuf x parts x 8KB
  char* ldsx = (char*)ldsx4;
  char* ldsw = (char*)ldsw4;

  const int tid = threadIdx.x;
  const int lane = tid & 63;
  const int wid = tid >> 6;
  const int mtile = blockIdx.x;
  const int rg = blockIdx.y;
  const int img = blockIdx.z;
  const u16* wps[3] = {W0, W1, W2};

  {  // stage X planes (reg-staged, swizzled: byte ^= (pixel&7)<<4)
    const u16* aps[3] = {A0, A1, A2};
    size_t abase = (size_t)img * PLANE + (size_t)rg * 4 * (PADW * 64);
#pragma unroll
    for (int pl = 0; pl < NPLANES; ++pl) {
      const u16* src = aps[pl] + abase;
      for (int q = tid; q < 1632; q += 256) {
        int p = q >> 3, g = q & 7;
        uint4 v = *reinterpret_cast<const uint4*>(src + p * 64 + g * 8);
        int byte = (p * 128 + g * 16) ^ ((p & 7) << 4);
        *reinterpret_cast<uint4*>(ldsx + pl * 26112 + byte) = v;
      }
    }
  }

  const size_t wrowbase = (size_t)mtile * 64 * 64;
  auto stageW = [&](int tap, int buf) {
#pragma unroll
    for (int part = 0; part < NPARTS; ++part) {
      const char* gsrc = (const char*)(wps[part] + (size_t)tap * Mtot * 64 + wrowbase);
#pragma unroll
      for (int half = 0; half < 2; ++half) {
        int L = half * 4096 + wid * 1024 + lane * 16;
        int srcb = L ^ (((L >> 7) & 7) << 4);   // inverse-swizzle the SOURCE
        gload16(gsrc + srcb, ldsw + buf * WBUF + part * 8192 + L);
      }
    }
  };
  stageW(0, 0);
  __syncthreads();

  f32x4 acc[2][4], acc2[2][4];
#pragma unroll
  for (int i = 0; i < 2; ++i)
#pragma unroll
    for (int j = 0; j < 4; ++j)
#pragma unroll
      for (int k = 0; k < 4; ++k) { acc[i][j][k] = 0.f; acc2[i][j][k] = 0.f; }

  const int wm = wid >> 1, wn = wid & 1;

  for (int tap = 0; tap < 9; ++tap) {
    if (tap < 8) stageW(tap + 1, (tap + 1) & 1);   // prefetch BEFORE compute
    char* wb = ldsw + (tap & 1) * WBUF;
    const int kh = tap / 3, kw = tap - kh * 3;
#pragma unroll
    for (int khalf = 0; khalf < 2; ++khalf) {
      short8 af[NPARTS][2];
#pragma unroll
      for (int part = 0; part < NPARTS; ++part)
#pragma unroll
        for (int fm = 0; fm < 2; ++fm) {
          int m = wm * 32 + fm * 16 + (lane & 15);
          int byte = (m * 128 + khalf * 64 + (lane >> 4) * 16) ^ ((m & 7) << 4);
          af[part][fm] = *reinterpret_cast<const short8*>(wb + part * 8192 + byte);
        }
#pragma unroll
      for (int pl = 0; pl < NPLANES; ++pl) {
        short8 bfr[4];
#pragma unroll
        for (int fn = 0; fn < 4; ++fn) {
          int p = wn * 64 + fn * 16 + (lane & 15);
          int r = p >> 5, w = p & 31;
          int pL = (r + kh) * PADW + (w + kw);
          int byte = (pL * 128 + khalf * 64 + (lane >> 4) * 16) ^ ((pL & 7) << 4);
          bfr[fn] = *reinterpret_cast<const short8*>(ldsx + pl * 26112 + byte);
        }
        if constexpr (MODE == 0) {
          __builtin_amdgcn_s_setprio(1);
#pragma unroll
          for (int fm = 0; fm < 2; ++fm)
#pragma unroll
            for (int fn = 0; fn < 4; ++fn)
              acc[fm][fn] = __builtin_amdgcn_mfma_f32_16x16x32_f16(af[0][fm], bfr[fn], acc[fm][fn], 0, 0, 0);
#pragma unroll
          for (int fm = 0; fm < 2; ++fm)
#pragma unroll
            for (int fn = 0; fn < 4; ++fn)
              acc2[fm][fn] = __builtin_amdgcn_mfma_f32_16x16x32_f16(af[1][fm], bfr[fn], acc2[fm][fn], 0, 0, 0);
          __builtin_amdgcn_s_setprio(0);
        } else {
          constexpr int npt[3] = {3, 2, 1};   // plane0: w1,w2,w3; plane1: w1,w2; plane2: w1
          __builtin_amdgcn_s_setprio(1);
#pragma unroll
          for (int part = 0; part < 3; ++part) {
            if (part < npt[pl]) {
#pragma unroll
              for (int fm = 0; fm < 2; ++fm)
#pragma unroll
                for (int fn = 0; fn < 4; ++fn)
                  acc[fm][fn] = __builtin_amdgcn_mfma_f32_16x16x32_bf16(af[part][fm], bfr[fn], acc[fm][fn], 0, 0, 0);
            }
          }
          __builtin_amdgcn_s_setprio(0);
        }
      }
    }
    __syncthreads();
  }

  // D layout: col=lane&15 (pixel), row=(lane>>4)*4+reg (m)
  size_t obase = (size_t)img * Mtot * 1024;
  const float S1 = 1.0f / 512.0f, S2 = 1.0f / 2097152.0f;
#pragma unroll
  for (int fm = 0; fm < 2; ++fm)
#pragma unroll
    for (int fn = 0; fn < 4; ++fn) {
      int pcol = rg * 128 + wn * 64 + fn * 16 + (lane & 15);
      int mrow0 = mtile * 64 + wm * 32 + fm * 16 + (lane >> 4) * 4;
#pragma unroll
      for (int r2 = 0; r2 < 4; ++r2) {
        float v;
        if constexpr (MODE == 0) v = acc[fm][fn][r2] * S1 + acc2[fm][fn][r2] * S2;
        else v = acc[fm][fn][r2];
        out[obase + (size_t)(mrow0 + r2) * 1024 + pcol] = v;
      }
    }
}

// Sequential LIF gate scan over a chunk of timesteps. f64 states, f32 conv inputs.
__global__ void scan_kernel(const float* __restrict__ wx,   // [nt*8][192][1024]
                            const float* __restrict__ wh,   // [8][192][1024]
                            const float* __restrict__ wcb,  // [8][128][1024]
                            const float* __restrict__ bih, const float* __restrict__ bhh,
                            const float* __restrict__ bch,
                            double* __restrict__ st, int t0, int nt) {
  const double DMI = 0.001 * 100.0;   // dt * tau_mem_inv
  const double DSI = 0.001 * 200.0;   // dt * tau_syn_inv
  int e = blockIdx.x * 256 + threadIdx.x;   // ((b*64+c)*1024)+hw
  int hw = e & 1023;
  int c = (e >> 10) & 63;
  int b = e >> 16;
  size_t o0 = ((size_t)b * 192 + c) * 1024 + hw;
  size_t w0 = ((size_t)b * 128 + c) * 1024 + hw;
  double cI = ((double)wh[o0] + (double)bhh[c]) + ((double)wcb[w0] + (double)bch[c]);
  double cF = ((double)wh[o0 + 64 * 1024] + (double)bhh[64 + c]) +
              ((double)wcb[w0 + 64 * 1024] + (double)bch[64 + c]);
  double cG = (double)wh[o0 + 128 * 1024] + (double)bhh[128 + c];
  double bI = (double)bih[c], bF = (double)bih[64 + c], bG = (double)bih[128 + c];

  double vi, ii, vf, fi, vg, gi, mi, mf, mg, mo;
  if (t0 == 0) {
    vi = ii = vf = fi = vg = gi = 0.0;
    mi = mf = mg = mo = -INFINITY;
  } else {
    vi = st[0 * NELEM + e]; ii = st[1 * NELEM + e];
    vf = st[2 * NELEM + e]; fi = st[3 * NELEM + e];
    vg = st[4 * NELEM + e]; gi = st[5 * NELEM + e];
    mi = st[6 * NELEM + e]; mf = st[7 * NELEM + e];
    mg = st[8 * NELEM + e]; mo = st[9 * NELEM + e];
  }
  for (int t = 0; t < nt; ++t) {
    const float* wp = wx + (size_t)(t * 8 + b) * (192 * 1024);
    double inpI = ((double)wp[(size_t)c * 1024 + hw] + bI) + cI;
    double inpF = ((double)wp[(size_t)(64 + c) * 1024 + hw] + bF) + cF;
    double inpG = ((double)wp[(size_t)(128 + c) * 1024 + hw] + bG) + cG;
    double vd = vi + DMI * (ii - vi);
    vi = (vd > 1.0) ? 0.0 : vd;
    ii = (ii - DSI * ii) + inpI;
    vd = vf + DMI * (fi - vf);
    vf = (vd > 1.0) ? 0.0 : vd;
    fi = (fi - DSI * fi) + inpF;
    vd = vg + DMI * (gi - vg);
    vg = (vd > 1.0) ? 0.0 : vd;
    gi = (gi - DSI * gi) + inpG;
    double vod = vg + DMI * (gi - vg);
    double vo = (vod > 1.0) ? 0.0 : vod;
    if (t0 + t >= 1) {
      mi = fmax(mi, vi); mf = fmax(mf, vf);
      mg = fmax(mg, vg); mo = fmax(mo, vo);
    }
  }
  st[0 * NELEM + e] = vi; st[1 * NELEM + e] = ii;
  st[2 * NELEM + e] = vf; st[3 * NELEM + e] = fi;
  st[4 * NELEM + e] = vg; st[5 * NELEM + e] = gi;
  st[6 * NELEM + e] = mi; st[7 * NELEM + e] = mf;
  st[8 * NELEM + e] = mg; st[9 * NELEM + e] = mo;
}

__global__ void final_kernel(const double* __restrict__ st, const float* __restrict__ c0,
                             float* __restrict__ out) {
  int e = blockIdx.x * 256 + threadIdx.x;
  double mi = st[6 * NELEM + e], mf = st[7 * NELEM + e];
  double mg = st[8 * NELEM + e], mo = st[9 * NELEM + e];
  double c1 = mf * (double)c0[e] + mi * mg;
  out[e] = (float)(mo * tanh(c1));
  out[NELEM + e] = (float)c1;
}

extern "C" void kernel_launch(void* const* d_in, const int* in_sizes, int n_in,
                              void* d_out, int out_size, void* d_ws, size_t ws_size,
                              hipStream_t stream) {
  const float* input = (const float*)d_in[0];
  const float* h0    = (const float*)d_in[1];
  const float* c0    = (const float*)d_in[2];
  const float* wih   = (const float*)d_in[3];
  const float* whh   = (const float*)d_in[4];
  const float* wch   = (const float*)d_in[5];
  const float* bih   = (const float*)d_in[6];
  const float* bhh   = (const float*)d_in[7];
  const float* bch   = (const float*)d_in[8];
  char* ws = (char*)d_ws;

  size_t off = 0;
  auto take = [&](size_t bytes) { size_t o = off; off += (bytes + 255) & ~(size_t)255; return o; };
  size_t oXp  = take((size_t)SEQ * 8 * PLANE * 2);     // zeroed region start
  size_t oH1  = take((size_t)8 * PLANE * 2);
  size_t oH2  = take((size_t)8 * PLANE * 2);
  size_t oH3  = take((size_t)8 * PLANE * 2);
  size_t oC1  = take((size_t)8 * PLANE * 2);
  size_t oC2  = take((size_t)8 * PLANE * 2);
  size_t oC3  = take((size_t)8 * PLANE * 2);
  size_t oIh1 = take((size_t)9 * 192 * 64 * 2);
  size_t oIh2 = take((size_t)9 * 192 * 64 * 2);
  size_t oHh1 = take((size_t)9 * 192 * 64 * 2);
  size_t oHh2 = take((size_t)9 * 192 * 64 * 2);
  size_t oHh3 = take((size_t)9 * 192 * 64 * 2);
  size_t oCh1 = take((size_t)9 * 128 * 64 * 2);
  size_t oCh2 = take((size_t)9 * 128 * 64 * 2);
  size_t oCh3 = take((size_t)9 * 128 * 64 * 2);
  size_t oWh  = take((size_t)8 * 192 * 1024 * 4);
  size_t oWc  = take((size_t)8 * 128 * 1024 * 4);
  size_t oSt  = take((size_t)10 * NELEM * 8);
  size_t fixedEnd = off;
  const size_t chunkBytes = (size_t)8 * 192 * 1024 * 4;  // per-timestep wx bytes
  int chunk = 32;
  while (chunk > 1 && fixedEnd + (size_t)chunk * chunkBytes > ws_size) chunk >>= 1;
  size_t oWx = fixedEnd;

  u16* xp  = (u16*)(ws + oXp);
  u16* h1p = (u16*)(ws + oH1); u16* h2p = (u16*)(ws + oH2); u16* h3p = (u16*)(ws + oH3);
  u16* c1p = (u16*)(ws + oC1); u16* c2p = (u16*)(ws + oC2); u16* c3p = (u16*)(ws + oC3);
  u16* ih1 = (u16*)(ws + oIh1); u16* ih2 = (u16*)(ws + oIh2);
  u16* hh1 = (u16*)(ws + oHh1); u16* hh2 = (u16*)(ws + oHh2); u16* hh3 = (u16*)(ws + oHh3);
  u16* ch1 = (u16*)(ws + oCh1); u16* ch2 = (u16*)(ws + oCh2); u16* ch3 = (u16*)(ws + oCh3);
  float* whb = (float*)(ws + oWh);
  float* wcb = (float*)(ws + oWc);
  double* st = (double*)(ws + oSt);
  float* wxb = (float*)(ws + oWx);

  // zero the padded-plane region (Xp + 6 h/c planes are contiguous)
  int nZero = (int)(((size_t)SEQ * 8 * PLANE * 2 + 6 * ((size_t)8 * PLANE * 2)) / 16);
  zero_kernel<<<2048, 256, 0, stream>>>((uint4*)(ws + oXp), nZero);
  encode_kernel<<<2048, 256, 0, stream>>>(input, xp);
  prep_hc_kernel<<<2048, 256, 0, stream>>>(h0, c0, h1p, h2p, h3p, c1p, c2p, c3p);
  prep_w_kernel<<<1152, 256, 0, stream>>>(wih, whh, wch, ih1, ih2,
                                          hh1, hh2, hh3, ch1, ch2, ch3);

  conv9_kernel<1><<<dim3(3, 8, 8), 256, 0, stream>>>(h1p, h2p, h3p, hh1, hh2, hh3, whb, 192);
  conv9_kernel<1><<<dim3(2, 8, 8), 256, 0, stream>>>(c1p, c2p, c3p, ch1, ch2, ch3, wcb, 128);

  for (int t0 = 0; t0 < SEQ; t0 += chunk) {
    conv9_kernel<0><<<dim3(3, 8, 8 * chunk), 256, 0, stream>>>(
        xp + (size_t)t0 * 8 * PLANE, xp, xp, ih1, ih2, ih2, wxb, 192);
    scan_kernel<<<2048, 256, 0, stream>>>(wxb, whb, wcb, bih, bhh, bch, st, t0, chunk);
  }
  final_kernel<<<2048, 256, 0, stream>>>(st, c0, (float*)d_out);
}

// Round 4
// 303.791 us; speedup vs baseline: 1.4815x; 1.1590x over previous
//
#include <hip/hip_runtime.h>
#include <hip/hip_bf16.h>
#include <hip/hip_fp16.h>

typedef unsigned short u16;
typedef __attribute__((ext_vector_type(8))) short short8;
typedef __attribute__((ext_vector_type(4))) float f32x4;

#define NELEM 524288          // 8*64*32*32
#define PADW 34
#define PLANE 73984           // 34*34*64 elements per padded image
#define SEQ 32

__device__ inline void split3(float v, u16& a, u16& b, u16& c) {
  __hip_bfloat16 h1 = __float2bfloat16(v);
  float r1 = v - __bfloat162float(h1);
  __hip_bfloat16 h2 = __float2bfloat16(r1);
  float r2 = r1 - __bfloat162float(h2);
  __hip_bfloat16 h3 = __float2bfloat16(r2);
  a = *reinterpret_cast<u16*>(&h1);
  b = *reinterpret_cast<u16*>(&h2);
  c = *reinterpret_cast<u16*>(&h3);
}

__device__ inline void gload16(const void* g, void* l) {
  typedef const __attribute__((address_space(1))) void* gp_t;
  typedef __attribute__((address_space(3))) void* lp_t;
  __builtin_amdgcn_global_load_lds((gp_t)g, (lp_t)l, 16, 0, 0);
}

// Constant-current LIF encoder in f64 over the PADDED plane (borders write 0,
// so no separate zero pass). x(t) f16 exact 0/1, layout xp[t][b][py][px][c].
__global__ void encode_kernel(const float* __restrict__ input, u16* __restrict__ xp) {
  int e = blockIdx.x * 256 + threadIdx.x;   // (b*1156 + pp)*64 + c ; 8*1156*64 total
  int c = e & 63;
  int pp = (e >> 6) % 1156;
  int b = e / (1156 * 64);
  int py = pp / 34, px = pp - py * 34;
  size_t base = (size_t)b * PLANE + (size_t)pp * 64 + c;
  bool interior = (py >= 1 && py <= 32 && px >= 1 && px <= 32);
  const double DMI = 0.001 * 100.0;
  double inp = interior ? (double)input[(size_t)(((b << 6) + c) << 10) + (py - 1) * 32 + (px - 1)] : 0.0;
  double ve = 0.0;
  for (int t = 0; t < SEQ; ++t) {
    double v = ve + DMI * (inp - ve);
    bool x = interior && (v > 1.0);
    ve = x ? 0.0 : v;
    xp[(size_t)t * (8 * PLANE) + base] = x ? (u16)0x3C00 : (u16)0;   // f16 1.0
  }
}

// h0 / c0 -> padded channel-last, 3-way bf16 split; covers pad region with zeros.
__global__ void prep_hc_kernel(const float* __restrict__ h0, const float* __restrict__ c0,
                               u16* __restrict__ h1, u16* __restrict__ h2, u16* __restrict__ h3,
                               u16* __restrict__ c1, u16* __restrict__ c2, u16* __restrict__ c3) {
  int e = blockIdx.x * 256 + threadIdx.x;   // (b*1156 + pp)*64 + c
  int c = e & 63;
  int pp = (e >> 6) % 1156;
  int b = e / (1156 * 64);
  int py = pp / 34, px = pp - py * 34;
  size_t dst = (size_t)b * PLANE + (size_t)pp * 64 + c;
  bool interior = (py >= 1 && py <= 32 && px >= 1 && px <= 32);
  u16 a = 0, bb = 0, cc = 0, d = 0, ee = 0, ff = 0;
  if (interior) {
    size_t src = (size_t)(((b << 6) + c) << 10) + (py - 1) * 32 + (px - 1);
    split3(h0[src], a, bb, cc);
    split3(c0[src], d, ee, ff);
  }
  h1[dst] = a; h2[dst] = bb; h3[dst] = cc;
  c1[dst] = d; c2[dst] = ee; c3[dst] = ff;
}

// Weights: ih -> f16 2-part with power-of-2 pre-scale; hh/ch -> bf16 3-part.
__global__ void prep_w_kernel(const float* __restrict__ wih, const float* __restrict__ whh,
                              const float* __restrict__ wch,
                              u16* __restrict__ ih1, u16* __restrict__ ih2,
                              u16* __restrict__ hh1, u16* __restrict__ hh2, u16* __restrict__ hh3,
                              u16* __restrict__ ch1, u16* __restrict__ ch2, u16* __restrict__ ch3) {
  int t = blockIdx.x * 256 + threadIdx.x;   // (tap*512 + row)*64 + c
  int c = t & 63;
  int row = (t >> 6) & 511;
  int tap = t >> 15;
  if (row < 192) {
    float v = wih[(size_t)((row << 6) + c) * 9 + tap] * 512.0f;
    __half a = __float2half(v);
    float r = (v - __half2float(a)) * 4096.0f;
    __half b = __float2half(r);
    size_t d = (size_t)(tap * 192 + row) * 64 + c;
    ih1[d] = *reinterpret_cast<u16*>(&a);
    ih2[d] = *reinterpret_cast<u16*>(&b);
  } else {
    const float* src; u16 *d1, *d2, *d3; int m, Mtot;
    if (row < 384) { src = whh; m = row - 192; Mtot = 192; d1 = hh1; d2 = hh2; d3 = hh3; }
    else           { src = wch; m = row - 384; Mtot = 128; d1 = ch1; d2 = ch2; d3 = ch3; }
    float v = src[(size_t)((m << 6) + c) * 9 + tap];
    u16 a, b, cc; split3(v, a, b, cc);
    size_t d = (size_t)(tap * Mtot + m) * 64 + c;
    d1[d] = a; d2[d] = b; d3[d] = cc;
  }
}

// wx conv: f16 spikes x 2 scaled f16 W parts. Block 256 thr = 4 waves (2m x 2n).
// Tile BM=64, BN=256 px (8 rows x 32). Wave: 32m x 128px = 2x8 frags, dual acc.
// Per wave-tap: 24 ds_read_b128 vs 64 MFMA -> MFMA-bound. 1 barrier/tap,
// W(tap+1) double-buffer prefetch via global_load_lds (pre-swizzled source).
__global__ __launch_bounds__(256, 2) void conv0_kernel(
    const u16* __restrict__ X, const u16* __restrict__ W1p, const u16* __restrict__ W2p,
    float* __restrict__ out) {
  __shared__ uint4 ldsx4[2720];    // 10 rows x 34 px x 128B = 43520 B
  __shared__ uint4 ldsw4[2048];    // dbuf(2) x parts(2) x 8KB = 32768 B
  char* ldsx = (char*)ldsx4;
  char* ldsw = (char*)ldsw4;

  const int tid = threadIdx.x;
  const int lane = tid & 63;
  const int wid = tid >> 6;
  const int mtile = blockIdx.x;     // 0..2
  const int rg = blockIdx.y;        // 0..3 (8 rows each)
  const int img = blockIdx.z;       // t*8 + b

  {  // stage X tile rows rg*8 .. rg*8+9 (reg-staged, swizzled byte ^= (p&7)<<4)
    const u16* src = X + (size_t)img * PLANE + (size_t)rg * 8 * (PADW * 64);
    for (int q = tid; q < 2720; q += 256) {
      int p = q >> 3, g = q & 7;
      uint4 v = *reinterpret_cast<const uint4*>(src + p * 64 + g * 8);
      int byte = (p * 128 + g * 16) ^ ((p & 7) << 4);
      *reinterpret_cast<uint4*>(ldsx + byte) = v;
    }
  }

  const u16* wps[2] = {W1p, W2p};
  const size_t wrowbase = (size_t)mtile * 64 * 64;
  auto stageW = [&](int tap, int buf) {
#pragma unroll
    for (int part = 0; part < 2; ++part) {
      const char* gsrc = (const char*)(wps[part] + (size_t)tap * 192 * 64 + wrowbase);
#pragma unroll
      for (int half = 0; half < 2; ++half) {
        int L = half * 4096 + wid * 1024 + lane * 16;
        int srcb = L ^ (((L >> 7) & 7) << 4);   // inverse-swizzle the SOURCE
        gload16(gsrc + srcb, ldsw + buf * 16384 + part * 8192 + L);
      }
    }
  };
  stageW(0, 0);
  __syncthreads();

  f32x4 acc[2][2][8];   // [part][fm][fn]
#pragma unroll
  for (int p = 0; p < 2; ++p)
#pragma unroll
    for (int i = 0; i < 2; ++i)
#pragma unroll
      for (int j = 0; j < 8; ++j)
#pragma unroll
        for (int k = 0; k < 4; ++k) acc[p][i][j][k] = 0.f;

  const int wm = wid >> 1, wn = wid & 1;

  for (int tap = 0; tap < 9; ++tap) {
    if (tap < 8) stageW(tap + 1, (tap + 1) & 1);   // prefetch BEFORE compute
    char* wb = ldsw + (tap & 1) * 16384;
    const int kh = tap / 3, kw = tap - kh * 3;
#pragma unroll
    for (int khalf = 0; khalf < 2; ++khalf) {
      short8 af[2][2];
#pragma unroll
      for (int part = 0; part < 2; ++part)
#pragma unroll
        for (int fm = 0; fm < 2; ++fm) {
          int m = wm * 32 + fm * 16 + (lane & 15);
          int byte = (m * 128 + khalf * 64 + (lane >> 4) * 16) ^ ((m & 7) << 4);
          af[part][fm] = *reinterpret_cast<const short8*>(wb + part * 8192 + byte);
        }
      short8 bfr[8];
#pragma unroll
      for (int fn = 0; fn < 8; ++fn) {
        int p = wn * 128 + fn * 16 + (lane & 15);
        int r = p >> 5, w = p & 31;
        int pL = (r + kh) * PADW + (w + kw);
        int byte = (pL * 128 + khalf * 64 + (lane >> 4) * 16) ^ ((pL & 7) << 4);
        bfr[fn] = *reinterpret_cast<const short8*>(ldsx + byte);
      }
      __builtin_amdgcn_s_setprio(1);
#pragma unroll
      for (int fm = 0; fm < 2; ++fm)
#pragma unroll
        for (int fn = 0; fn < 8; ++fn)
          acc[0][fm][fn] = __builtin_amdgcn_mfma_f32_16x16x32_f16(af[0][fm], bfr[fn], acc[0][fm][fn], 0, 0, 0);
#pragma unroll
      for (int fm = 0; fm < 2; ++fm)
#pragma unroll
        for (int fn = 0; fn < 8; ++fn)
          acc[1][fm][fn] = __builtin_amdgcn_mfma_f32_16x16x32_f16(af[1][fm], bfr[fn], acc[1][fm][fn], 0, 0, 0);
      __builtin_amdgcn_s_setprio(0);
    }
    __syncthreads();
  }

  // D layout: col=lane&15 (pixel), row=(lane>>4)*4+reg (m)
  size_t obase = (size_t)img * (192 * 1024);
  const float S1 = 1.0f / 512.0f, S2 = 1.0f / 2097152.0f;
#pragma unroll
  for (int fm = 0; fm < 2; ++fm)
#pragma unroll
    for (int fn = 0; fn < 8; ++fn) {
      int pcol = rg * 256 + wn * 128 + fn * 16 + (lane & 15);
      int mrow0 = mtile * 64 + wm * 32 + fm * 16 + (lane >> 4) * 4;
#pragma unroll
      for (int r2 = 0; r2 < 4; ++r2)
        out[obase + (size_t)(mrow0 + r2) * 1024 + pcol] =
            acc[0][fm][fn][r2] * S1 + acc[1][fm][fn][r2] * S2;
    }
}

// wh + wc conv merged: bf16 3-plane x 3-part, 6 cross terms. Block 256 thr,
// BM=64, BN=128 px. blockIdx.x: 0-2 -> wh (Mtot 192), 3-4 -> wc (Mtot 128).
__global__ __launch_bounds__(256) void conv1_kernel(
    const u16* __restrict__ Ah0, const u16* __restrict__ Ah1, const u16* __restrict__ Ah2,
    const u16* __restrict__ Ac0, const u16* __restrict__ Ac1, const u16* __restrict__ Ac2,
    const u16* __restrict__ Wh0, const u16* __restrict__ Wh1, const u16* __restrict__ Wh2,
    const u16* __restrict__ Wc0, const u16* __restrict__ Wc1, const u16* __restrict__ Wc2,
    float* __restrict__ outh, float* __restrict__ outc) {
  __shared__ uint4 ldsx4[3 * 1632];
  __shared__ uint4 ldsw4[2 * 3 * 512];
  char* ldsx = (char*)ldsx4;
  char* ldsw = (char*)ldsw4;

  const int tid = threadIdx.x;
  const int lane = tid & 63;
  const int wid = tid >> 6;
  const bool isC = blockIdx.x >= 3;
  const int mtile = isC ? blockIdx.x - 3 : blockIdx.x;
  const int Mtot = isC ? 128 : 192;
  const int rg = blockIdx.y;
  const int img = blockIdx.z;
  const u16* aps[3] = {isC ? Ac0 : Ah0, isC ? Ac1 : Ah1, isC ? Ac2 : Ah2};
  const u16* wps[3] = {isC ? Wc0 : Wh0, isC ? Wc1 : Wh1, isC ? Wc2 : Wh2};
  float* out = isC ? outc : outh;

  {  // stage 3 X planes (6 rows x 34 x 64ch each)
    size_t abase = (size_t)img * PLANE + (size_t)rg * 4 * (PADW * 64);
#pragma unroll
    for (int pl = 0; pl < 3; ++pl) {
      const u16* src = aps[pl] + abase;
      for (int q = tid; q < 1632; q += 256) {
        int p = q >> 3, g = q & 7;
        uint4 v = *reinterpret_cast<const uint4*>(src + p * 64 + g * 8);
        int byte = (p * 128 + g * 16) ^ ((p & 7) << 4);
        *reinterpret_cast<uint4*>(ldsx + pl * 26112 + byte) = v;
      }
    }
  }

  const size_t wrowbase = (size_t)mtile * 64 * 64;
  auto stageW = [&](int tap, int buf) {
#pragma unroll
    for (int part = 0; part < 3; ++part) {
      const char* gsrc = (const char*)(wps[part] + (size_t)tap * Mtot * 64 + wrowbase);
#pragma unroll
      for (int half = 0; half < 2; ++half) {
        int L = half * 4096 + wid * 1024 + lane * 16;
        int srcb = L ^ (((L >> 7) & 7) << 4);
        gload16(gsrc + srcb, ldsw + buf * 24576 + part * 8192 + L);
      }
    }
  };
  stageW(0, 0);
  __syncthreads();

  f32x4 acc[2][4];
#pragma unroll
  for (int i = 0; i < 2; ++i)
#pragma unroll
    for (int j = 0; j < 4; ++j)
#pragma unroll
      for (int k = 0; k < 4; ++k) acc[i][j][k] = 0.f;

  const int wm = wid >> 1, wn = wid & 1;

  for (int tap = 0; tap < 9; ++tap) {
    if (tap < 8) stageW(tap + 1, (tap + 1) & 1);
    char* wb = ldsw + (tap & 1) * 24576;
    const int kh = tap / 3, kw = tap - kh * 3;
#pragma unroll
    for (int khalf = 0; khalf < 2; ++khalf) {
      short8 af[3][2];
#pragma unroll
      for (int part = 0; part < 3; ++part)
#pragma unroll
        for (int fm = 0; fm < 2; ++fm) {
          int m = wm * 32 + fm * 16 + (lane & 15);
          int byte = (m * 128 + khalf * 64 + (lane >> 4) * 16) ^ ((m & 7) << 4);
          af[part][fm] = *reinterpret_cast<const short8*>(wb + part * 8192 + byte);
        }
#pragma unroll
      for (int pl = 0; pl < 3; ++pl) {
        short8 bfr[4];
#pragma unroll
        for (int fn = 0; fn < 4; ++fn) {
          int p = wn * 64 + fn * 16 + (lane & 15);
          int r = p >> 5, w = p & 31;
          int pL = (r + kh) * PADW + (w + kw);
          int byte = (pL * 128 + khalf * 64 + (lane >> 4) * 16) ^ ((pL & 7) << 4);
          bfr[fn] = *reinterpret_cast<const short8*>(ldsx + pl * 26112 + byte);
        }
        constexpr int npt[3] = {3, 2, 1};
        __builtin_amdgcn_s_setprio(1);
#pragma unroll
        for (int part = 0; part < 3; ++part) {
          if (part < npt[pl]) {
#pragma unroll
            for (int fm = 0; fm < 2; ++fm)
#pragma unroll
              for (int fn = 0; fn < 4; ++fn)
                acc[fm][fn] = __builtin_amdgcn_mfma_f32_16x16x32_bf16(af[part][fm], bfr[fn], acc[fm][fn], 0, 0, 0);
          }
        }
        __builtin_amdgcn_s_setprio(0);
      }
    }
    __syncthreads();
  }

  size_t obase = (size_t)img * Mtot * 1024;
#pragma unroll
  for (int fm = 0; fm < 2; ++fm)
#pragma unroll
    for (int fn = 0; fn < 4; ++fn) {
      int pcol = rg * 128 + wn * 64 + fn * 16 + (lane & 15);
      int mrow0 = mtile * 64 + wm * 32 + fm * 16 + (lane >> 4) * 4;
#pragma unroll
      for (int r2 = 0; r2 < 4; ++r2)
        out[obase + (size_t)(mrow0 + r2) * 1024 + pcol] = acc[fm][fn][r2];
    }
}

// Sequential LIF gate scan. f64 states, f32 conv inputs. Last chunk fuses the
// c1/h1 epilogue and skips the state writeback.
__global__ void scan_kernel(const float* __restrict__ wx,   // [nt*8][192][1024]
                            const float* __restrict__ wh,   // [8][192][1024]
                            const float* __restrict__ wcb,  // [8][128][1024]
                            const float* __restrict__ bih, const float* __restrict__ bhh,
                            const float* __restrict__ bch,
                            double* __restrict__ st, const float* __restrict__ c0,
                            float* __restrict__ outp, int t0, int nt) {
  const double DMI = 0.001 * 100.0;   // dt * tau_mem_inv
  const double DSI = 0.001 * 200.0;   // dt * tau_syn_inv
  int e = blockIdx.x * 256 + threadIdx.x;   // ((b*64+c)*1024)+hw
  int hw = e & 1023;
  int c = (e >> 10) & 63;
  int b = e >> 16;
  size_t o0 = ((size_t)b * 192 + c) * 1024 + hw;
  size_t w0 = ((size_t)b * 128 + c) * 1024 + hw;
  double cI = ((double)wh[o0] + (double)bhh[c]) + ((double)wcb[w0] + (double)bch[c]);
  double cF = ((double)wh[o0 + 64 * 1024] + (double)bhh[64 + c]) +
              ((double)wcb[w0 + 64 * 1024] + (double)bch[64 + c]);
  double cG = (double)wh[o0 + 128 * 1024] + (double)bhh[128 + c];
  double bI = (double)bih[c], bF = (double)bih[64 + c], bG = (double)bih[128 + c];

  double vi, ii, vf, fi, vg, gi, mi, mf, mg, mo;
  if (t0 == 0) {
    vi = ii = vf = fi = vg = gi = 0.0;
    mi = mf = mg = mo = -INFINITY;
  } else {
    vi = st[0 * NELEM + e]; ii = st[1 * NELEM + e];
    vf = st[2 * NELEM + e]; fi = st[3 * NELEM + e];
    vg = st[4 * NELEM + e]; gi = st[5 * NELEM + e];
    mi = st[6 * NELEM + e]; mf = st[7 * NELEM + e];
    mg = st[8 * NELEM + e]; mo = st[9 * NELEM + e];
  }
  for (int t = 0; t < nt; ++t) {
    const float* wp = wx + (size_t)(t * 8 + b) * (192 * 1024);
    double inpI = ((double)wp[(size_t)c * 1024 + hw] + bI) + cI;
    double inpF = ((double)wp[(size_t)(64 + c) * 1024 + hw] + bF) + cF;
    double inpG = ((double)wp[(size_t)(128 + c) * 1024 + hw] + bG) + cG;
    double vd = vi + DMI * (ii - vi);
    vi = (vd > 1.0) ? 0.0 : vd;
    ii = (ii - DSI * ii) + inpI;
    vd = vf + DMI * (fi - vf);
    vf = (vd > 1.0) ? 0.0 : vd;
    fi = (fi - DSI * fi) + inpF;
    vd = vg + DMI * (gi - vg);
    vg = (vd > 1.0) ? 0.0 : vd;
    gi = (gi - DSI * gi) + inpG;
    double vod = vg + DMI * (gi - vg);
    double vo = (vod > 1.0) ? 0.0 : vod;
    if (t0 + t >= 1) {
      mi = fmax(mi, vi); mf = fmax(mf, vf);
      mg = fmax(mg, vg); mo = fmax(mo, vo);
    }
  }
  if (t0 + nt >= SEQ) {
    double c1 = mf * (double)c0[e] + mi * mg;
    outp[e] = (float)(mo * tanh(c1));
    outp[NELEM + e] = (float)c1;
  } else {
    st[0 * NELEM + e] = vi; st[1 * NELEM + e] = ii;
    st[2 * NELEM + e] = vf; st[3 * NELEM + e] = fi;
    st[4 * NELEM + e] = vg; st[5 * NELEM + e] = gi;
    st[6 * NELEM + e] = mi; st[7 * NELEM + e] = mf;
    st[8 * NELEM + e] = mg; st[9 * NELEM + e] = mo;
  }
}

extern "C" void kernel_launch(void* const* d_in, const int* in_sizes, int n_in,
                              void* d_out, int out_size, void* d_ws, size_t ws_size,
                              hipStream_t stream) {
  const float* input = (const float*)d_in[0];
  const float* h0    = (const float*)d_in[1];
  const float* c0    = (const float*)d_in[2];
  const float* wih   = (const float*)d_in[3];
  const float* whh   = (const float*)d_in[4];
  const float* wch   = (const float*)d_in[5];
  const float* bih   = (const float*)d_in[6];
  const float* bhh   = (const float*)d_in[7];
  const float* bch   = (const float*)d_in[8];
  char* ws = (char*)d_ws;

  size_t off = 0;
  auto take = [&](size_t bytes) { size_t o = off; off += (bytes + 255) & ~(size_t)255; return o; };
  size_t oXp  = take((size_t)SEQ * 8 * PLANE * 2);
  size_t oH1  = take((size_t)8 * PLANE * 2);
  size_t oH2  = take((size_t)8 * PLANE * 2);
  size_t oH3  = take((size_t)8 * PLANE * 2);
  size_t oC1  = take((size_t)8 * PLANE * 2);
  size_t oC2  = take((size_t)8 * PLANE * 2);
  size_t oC3  = take((size_t)8 * PLANE * 2);
  size_t oIh1 = take((size_t)9 * 192 * 64 * 2);
  size_t oIh2 = take((size_t)9 * 192 * 64 * 2);
  size_t oHh1 = take((size_t)9 * 192 * 64 * 2);
  size_t oHh2 = take((size_t)9 * 192 * 64 * 2);
  size_t oHh3 = take((size_t)9 * 192 * 64 * 2);
  size_t oCh1 = take((size_t)9 * 128 * 64 * 2);
  size_t oCh2 = take((size_t)9 * 128 * 64 * 2);
  size_t oCh3 = take((size_t)9 * 128 * 64 * 2);
  size_t oWh  = take((size_t)8 * 192 * 1024 * 4);
  size_t oWc  = take((size_t)8 * 128 * 1024 * 4);
  size_t oSt  = take((size_t)10 * NELEM * 8);
  size_t fixedEnd = off;
  const size_t chunkBytes = (size_t)8 * 192 * 1024 * 4;  // per-timestep wx bytes
  int chunk = 32;
  while (chunk > 1 && fixedEnd + (size_t)chunk * chunkBytes > ws_size) chunk >>= 1;
  size_t oWx = fixedEnd;

  u16* xp  = (u16*)(ws + oXp);
  u16* h1p = (u16*)(ws + oH1); u16* h2p = (u16*)(ws + oH2); u16* h3p = (u16*)(ws + oH3);
  u16* c1p = (u16*)(ws + oC1); u16* c2p = (u16*)(ws + oC2); u16* c3p = (u16*)(ws + oC3);
  u16* ih1 = (u16*)(ws + oIh1); u16* ih2 = (u16*)(ws + oIh2);
  u16* hh1 = (u16*)(ws + oHh1); u16* hh2 = (u16*)(ws + oHh2); u16* hh3 = (u16*)(ws + oHh3);
  u16* ch1 = (u16*)(ws + oCh1); u16* ch2 = (u16*)(ws + oCh2); u16* ch3 = (u16*)(ws + oCh3);
  float* whb = (float*)(ws + oWh);
  float* wcb = (float*)(ws + oWc);
  double* st = (double*)(ws + oSt);
  float* wxb = (float*)(ws + oWx);

  encode_kernel<<<2312, 256, 0, stream>>>(input, xp);
  prep_hc_kernel<<<2312, 256, 0, stream>>>(h0, c0, h1p, h2p, h3p, c1p, c2p, c3p);
  prep_w_kernel<<<1152, 256, 0, stream>>>(wih, whh, wch, ih1, ih2,
                                          hh1, hh2, hh3, ch1, ch2, ch3);

  conv1_kernel<<<dim3(5, 8, 8), 256, 0, stream>>>(
      h1p, h2p, h3p, c1p, c2p, c3p,
      hh1, hh2, hh3, ch1, ch2, ch3, whb, wcb);

  for (int t0 = 0; t0 < SEQ; t0 += chunk) {
    conv0_kernel<<<dim3(3, 4, 8 * chunk), 256, 0, stream>>>(
        xp + (size_t)t0 * 8 * PLANE, ih1, ih2, wxb);
    scan_kernel<<<2048, 256, 0, stream>>>(wxb, whb, wcb, bih, bhh, bch,
                                          st, c0, (float*)d_out, t0, chunk);
  }
}

// Round 5
// 280.611 us; speedup vs baseline: 1.6039x; 1.0826x over previous
//
#include <hip/hip_runtime.h>
#include <hip/hip_bf16.h>
#include <hip/hip_fp16.h>

typedef unsigned short u16;
typedef signed char s8;
typedef __attribute__((ext_vector_type(8))) short short8;
typedef __attribute__((ext_vector_type(4))) float f32x4;
typedef __attribute__((ext_vector_type(4))) int i32x4;

#define NELEM 524288          // 8*64*32*32
#define PADW 34
#define PLANE 73984           // 34*34*64 elements per padded image
#define SEQ 32

__device__ inline void split3(float v, u16& a, u16& b, u16& c) {
  __hip_bfloat16 h1 = __float2bfloat16(v);
  float r1 = v - __bfloat162float(h1);
  __hip_bfloat16 h2 = __float2bfloat16(r1);
  float r2 = r1 - __bfloat162float(h2);
  __hip_bfloat16 h3 = __float2bfloat16(r2);
  a = *reinterpret_cast<u16*>(&h1);
  b = *reinterpret_cast<u16*>(&h2);
  c = *reinterpret_cast<u16*>(&h3);
}

__device__ inline void gload16(const void* g, void* l) {
  typedef const __attribute__((address_space(1))) void* gp_t;
  typedef __attribute__((address_space(3))) void* lp_t;
  __builtin_amdgcn_global_load_lds((gp_t)g, (lp_t)l, 16, 0, 0);
}

// Constant-current LIF encoder in f64 over the PADDED plane (borders write 0).
// x(t) i8 exact 0/1, layout xp[t][b][py][px][c].
__global__ void encode_kernel(const float* __restrict__ input, s8* __restrict__ xp) {
  int e = blockIdx.x * 256 + threadIdx.x;   // (b*1156 + pp)*64 + c ; 8*1156*64 total
  int c = e & 63;
  int pp = (e >> 6) % 1156;
  int b = e / (1156 * 64);
  int py = pp / 34, px = pp - py * 34;
  size_t base = (size_t)b * PLANE + (size_t)pp * 64 + c;
  bool interior = (py >= 1 && py <= 32 && px >= 1 && px <= 32);
  const double DMI = 0.001 * 100.0;
  double inp = interior ? (double)input[(size_t)(((b << 6) + c) << 10) + (py - 1) * 32 + (px - 1)] : 0.0;
  double ve = 0.0;
  for (int t = 0; t < SEQ; ++t) {
    double v = ve + DMI * (inp - ve);
    bool x = interior && (v > 1.0);
    ve = x ? 0.0 : v;
    xp[(size_t)t * (8 * PLANE) + base] = x ? (s8)1 : (s8)0;
  }
}

// h0 / c0 -> padded channel-last, 3-way bf16 split; covers pad region with zeros.
__global__ void prep_hc_kernel(const float* __restrict__ h0, const float* __restrict__ c0,
                               u16* __restrict__ h1, u16* __restrict__ h2, u16* __restrict__ h3,
                               u16* __restrict__ c1, u16* __restrict__ c2, u16* __restrict__ c3) {
  int e = blockIdx.x * 256 + threadIdx.x;   // (b*1156 + pp)*64 + c
  int c = e & 63;
  int pp = (e >> 6) % 1156;
  int b = e / (1156 * 64);
  int py = pp / 34, px = pp - py * 34;
  size_t dst = (size_t)b * PLANE + (size_t)pp * 64 + c;
  bool interior = (py >= 1 && py <= 32 && px >= 1 && px <= 32);
  u16 a = 0, bb = 0, cc = 0, d = 0, ee = 0, ff = 0;
  if (interior) {
    size_t src = (size_t)(((b << 6) + c) << 10) + (py - 1) * 32 + (px - 1);
    split3(h0[src], a, bb, cc);
    split3(c0[src], d, ee, ff);
  }
  h1[dst] = a; h2[dst] = bb; h3[dst] = cc;
  c1[dst] = d; c2[dst] = ee; c3[dst] = ff;
}

// Weights: ih -> EXACT 24-bit fixed point, 3 signed-byte parts:
//   W24 = round(w*2^28) (|W24| < 2^23 since |w| <= 1/48), W24 = b2*2^16 + b1*2^8 + b0.
// hh/ch -> bf16 3-part (unchanged). o-gate rows are dead.
__global__ void prep_w_kernel(const float* __restrict__ wih, const float* __restrict__ whh,
                              const float* __restrict__ wch,
                              s8* __restrict__ iq0, s8* __restrict__ iq1, s8* __restrict__ iq2,
                              u16* __restrict__ hh1, u16* __restrict__ hh2, u16* __restrict__ hh3,
                              u16* __restrict__ ch1, u16* __restrict__ ch2, u16* __restrict__ ch3) {
  int t = blockIdx.x * 256 + threadIdx.x;   // (tap*512 + row)*64 + c
  int c = t & 63;
  int row = (t >> 6) & 511;
  int tap = t >> 15;
  if (row < 192) {
    float v = wih[(size_t)((row << 6) + c) * 9 + tap];
    int Wi = (int)llrint((double)v * 268435456.0);
    int b0 = (Wi << 24) >> 24;
    int W1 = (Wi - b0) >> 8;
    int b1 = (W1 << 24) >> 24;
    int b2 = (W1 - b1) >> 8;
    size_t d = (size_t)(tap * 192 + row) * 64 + c;
    iq0[d] = (s8)b0; iq1[d] = (s8)b1; iq2[d] = (s8)b2;
  } else {
    const float* src; u16 *d1, *d2, *d3; int m, Mtot;
    if (row < 384) { src = whh; m = row - 192; Mtot = 192; d1 = hh1; d2 = hh2; d3 = hh3; }
    else           { src = wch; m = row - 384; Mtot = 128; d1 = ch1; d2 = ch2; d3 = ch3; }
    float v = src[(size_t)((m << 6) + c) * 9 + tap];
    u16 a, b, cc; split3(v, a, b, cc);
    size_t d = (size_t)(tap * Mtot + m) * 64 + c;
    d1[d] = a; d2[d] = b; d3[d] = cc;
  }
}

// wx conv, EXACT int8: spikes {0,1} x 3 byte-parts of 24-bit weights.
// mfma_i32_16x16x64_i8, K=64 = full channel depth -> one k-step per tap.
// Block 256 thr = 4 waves (2m x 2n). Tile BM=64, BN=256 px. Wave: 32m x 128px.
// Per wave-tap: 14 ds_read_b128 (8 B shared by all parts + 3x2 A) vs 48 MFMA.
// i8 rows are 64 B; swizzle byte ^= ((row>>1)&3)<<4 (involution, bank-even).
__global__ __launch_bounds__(256, 2) void conv0_kernel(
    const s8* __restrict__ X, const s8* __restrict__ W0p, const s8* __restrict__ W1p,
    const s8* __restrict__ W2p, float* __restrict__ out) {
  __shared__ uint4 ldsx4[1360];    // 10 rows x 34 px x 64 B = 21760 B
  __shared__ uint4 ldsw4[1536];    // dbuf(2) x parts(3) x 4 KB = 24576 B
  char* ldsx = (char*)ldsx4;
  char* ldsw = (char*)ldsw4;

  const int tid = threadIdx.x;
  const int lane = tid & 63;
  const int wid = tid >> 6;
  const int mtile = blockIdx.x;     // 0..2
  const int rg = blockIdx.y;        // 0..3 (8 rows each)
  const int img = blockIdx.z;       // t*8 + b

  {  // stage X tile via global_load_lds: linear LDS dest, inverse-swizzled source
    const char* src = (const char*)X + (size_t)img * PLANE + (size_t)rg * 8 * (PADW * 64);
    for (int q = tid; q < 1360; q += 256) {
      int L = q << 4;
      gload16(src + (L ^ (((L >> 7) & 3) << 4)), ldsx + L);
    }
  }

  const s8* wps[3] = {W0p, W1p, W2p};
  const size_t wbase = (size_t)mtile * 64 * 64;
  auto stageW = [&](int tap, int buf) {
#pragma unroll
    for (int part = 0; part < 3; ++part) {
      const char* gsrc = (const char*)(wps[part] + (size_t)tap * 192 * 64 + wbase);
      int L = (tid & 255) << 4;    // 256 granules of 16 B = 4 KB tile
      gload16(gsrc + (L ^ (((L >> 7) & 3) << 4)), ldsw + buf * 12288 + part * 4096 + L);
    }
  };
  stageW(0, 0);
  __syncthreads();

  i32x4 acc[3][2][8];   // [part][fm][fn] -- i32 exact
#pragma unroll
  for (int p = 0; p < 3; ++p)
#pragma unroll
    for (int i = 0; i < 2; ++i)
#pragma unroll
      for (int j = 0; j < 8; ++j)
#pragma unroll
        for (int k = 0; k < 4; ++k) acc[p][i][j][k] = 0;

  const int wm = wid >> 1, wn = wid & 1;
  const int kg = lane >> 4;         // k-group: 16 consecutive channels

  for (int tap = 0; tap < 9; ++tap) {
    if (tap < 8) stageW(tap + 1, (tap + 1) & 1);   // prefetch BEFORE compute
    char* wb = ldsw + (tap & 1) * 12288;
    const int kh = tap / 3, kw = tap - kh * 3;
    i32x4 bfr[8];
#pragma unroll
    for (int fn = 0; fn < 8; ++fn) {
      int p = wn * 128 + fn * 16 + (lane & 15);
      int r = p >> 5, w = p & 31;
      int pL = (r + kh) * PADW + (w + kw);
      int byte = (pL * 64 + kg * 16) ^ (((pL >> 1) & 3) << 4);
      bfr[fn] = *reinterpret_cast<const i32x4*>(ldsx + byte);
    }
#pragma unroll
    for (int part = 0; part < 3; ++part) {
      i32x4 af[2];
#pragma unroll
      for (int fm = 0; fm < 2; ++fm) {
        int m = wm * 32 + fm * 16 + (lane & 15);
        int byte = (m * 64 + kg * 16) ^ (((m >> 1) & 3) << 4);
        af[fm] = *reinterpret_cast<const i32x4*>(wb + part * 4096 + byte);
      }
      __builtin_amdgcn_s_setprio(1);
#pragma unroll
      for (int fm = 0; fm < 2; ++fm)
#pragma unroll
        for (int fn = 0; fn < 8; ++fn)
          acc[part][fm][fn] = __builtin_amdgcn_mfma_i32_16x16x64_i8(af[fm], bfr[fn], acc[part][fm][fn], 0, 0, 0);
      __builtin_amdgcn_s_setprio(0);
    }
    __syncthreads();
  }

  // D layout: col=lane&15 (pixel), row=(lane>>4)*4+reg (m). Exact recombine.
  size_t obase = (size_t)img * (192 * 1024);
  const double S0 = 1.0 / 268435456.0;   // 2^-28
#pragma unroll
  for (int fm = 0; fm < 2; ++fm)
#pragma unroll
    for (int fn = 0; fn < 8; ++fn) {
      int pcol = rg * 256 + wn * 128 + fn * 16 + (lane & 15);
      int mrow0 = mtile * 64 + wm * 32 + fm * 16 + (lane >> 4) * 4;
#pragma unroll
      for (int r2 = 0; r2 < 4; ++r2) {
        long long tot = ((long long)acc[2][fm][fn][r2] << 16) +
                        ((long long)acc[1][fm][fn][r2] << 8) +
                        (long long)acc[0][fm][fn][r2];
        out[obase + (size_t)(mrow0 + r2) * 1024 + pcol] = (float)((double)tot * S0);
      }
    }
}

// wh + wc conv merged: bf16 3-plane x 3-part, 6 cross terms. Block 256 thr,
// BM=64, BN=128 px. blockIdx.x: 0-2 -> wh (Mtot 192), 3-4 -> wc (Mtot 128).
__global__ __launch_bounds__(256) void conv1_kernel(
    const u16* __restrict__ Ah0, const u16* __restrict__ Ah1, const u16* __restrict__ Ah2,
    const u16* __restrict__ Ac0, const u16* __restrict__ Ac1, const u16* __restrict__ Ac2,
    const u16* __restrict__ Wh0, const u16* __restrict__ Wh1, const u16* __restrict__ Wh2,
    const u16* __restrict__ Wc0, const u16* __restrict__ Wc1, const u16* __restrict__ Wc2,
    float* __restrict__ outh, float* __restrict__ outc) {
  __shared__ uint4 ldsx4[3 * 1632];
  __shared__ uint4 ldsw4[2 * 3 * 512];
  char* ldsx = (char*)ldsx4;
  char* ldsw = (char*)ldsw4;

  const int tid = threadIdx.x;
  const int lane = tid & 63;
  const int wid = tid >> 6;
  const bool isC = blockIdx.x >= 3;
  const int mtile = isC ? blockIdx.x - 3 : blockIdx.x;
  const int Mtot = isC ? 128 : 192;
  const int rg = blockIdx.y;
  const int img = blockIdx.z;
  const u16* aps[3] = {isC ? Ac0 : Ah0, isC ? Ac1 : Ah1, isC ? Ac2 : Ah2};
  const u16* wps[3] = {isC ? Wc0 : Wh0, isC ? Wc1 : Wh1, isC ? Wc2 : Wh2};
  float* out = isC ? outc : outh;

  {  // stage 3 X planes (6 rows x 34 x 64ch each)
    size_t abase = (size_t)img * PLANE + (size_t)rg * 4 * (PADW * 64);
#pragma unroll
    for (int pl = 0; pl < 3; ++pl) {
      const u16* src = aps[pl] + abase;
      for (int q = tid; q < 1632; q += 256) {
        int p = q >> 3, g = q & 7;
        uint4 v = *reinterpret_cast<const uint4*>(src + p * 64 + g * 8);
        int byte = (p * 128 + g * 16) ^ ((p & 7) << 4);
        *reinterpret_cast<uint4*>(ldsx + pl * 26112 + byte) = v;
      }
    }
  }

  const size_t wrowbase = (size_t)mtile * 64 * 64;
  auto stageW = [&](int tap, int buf) {
#pragma unroll
    for (int part = 0; part < 3; ++part) {
      const char* gsrc = (const char*)(wps[part] + (size_t)tap * Mtot * 64 + wrowbase);
#pragma unroll
      for (int half = 0; half < 2; ++half) {
        int L = half * 4096 + wid * 1024 + lane * 16;
        int srcb = L ^ (((L >> 7) & 7) << 4);
        gload16(gsrc + srcb, ldsw + buf * 24576 + part * 8192 + L);
      }
    }
  };
  stageW(0, 0);
  __syncthreads();

  f32x4 acc[2][4];
#pragma unroll
  for (int i = 0; i < 2; ++i)
#pragma unroll
    for (int j = 0; j < 4; ++j)
#pragma unroll
      for (int k = 0; k < 4; ++k) acc[i][j][k] = 0.f;

  const int wm = wid >> 1, wn = wid & 1;

  for (int tap = 0; tap < 9; ++tap) {
    if (tap < 8) stageW(tap + 1, (tap + 1) & 1);
    char* wb = ldsw + (tap & 1) * 24576;
    const int kh = tap / 3, kw = tap - kh * 3;
#pragma unroll
    for (int khalf = 0; khalf < 2; ++khalf) {
      short8 af[3][2];
#pragma unroll
      for (int part = 0; part < 3; ++part)
#pragma unroll
        for (int fm = 0; fm < 2; ++fm) {
          int m = wm * 32 + fm * 16 + (lane & 15);
          int byte = (m * 128 + khalf * 64 + (lane >> 4) * 16) ^ ((m & 7) << 4);
          af[part][fm] = *reinterpret_cast<const short8*>(wb + part * 8192 + byte);
        }
#pragma unroll
      for (int pl = 0; pl < 3; ++pl) {
        short8 bfr[4];
#pragma unroll
        for (int fn = 0; fn < 4; ++fn) {
          int p = wn * 64 + fn * 16 + (lane & 15);
          int r = p >> 5, w = p & 31;
          int pL = (r + kh) * PADW + (w + kw);
          int byte = (pL * 128 + khalf * 64 + (lane >> 4) * 16) ^ ((pL & 7) << 4);
          bfr[fn] = *reinterpret_cast<const short8*>(ldsx + pl * 26112 + byte);
        }
        constexpr int npt[3] = {3, 2, 1};
        __builtin_amdgcn_s_setprio(1);
#pragma unroll
        for (int part = 0; part < 3; ++part) {
          if (part < npt[pl]) {
#pragma unroll
            for (int fm = 0; fm < 2; ++fm)
#pragma unroll
              for (int fn = 0; fn < 4; ++fn)
                acc[fm][fn] = __builtin_amdgcn_mfma_f32_16x16x32_bf16(af[part][fm], bfr[fn], acc[fm][fn], 0, 0, 0);
          }
        }
        __builtin_amdgcn_s_setprio(0);
      }
    }
    __syncthreads();
  }

  size_t obase = (size_t)img * Mtot * 1024;
#pragma unroll
  for (int fm = 0; fm < 2; ++fm)
#pragma unroll
    for (int fn = 0; fn < 4; ++fn) {
      int pcol = rg * 128 + wn * 64 + fn * 16 + (lane & 15);
      int mrow0 = mtile * 64 + wm * 32 + fm * 16 + (lane >> 4) * 4;
#pragma unroll
      for (int r2 = 0; r2 < 4; ++r2)
        out[obase + (size_t)(mrow0 + r2) * 1024 + pcol] = acc[fm][fn][r2];
    }
}

// Sequential LIF gate scan. f64 states, f32 conv inputs. Last chunk fuses the
// c1/h1 epilogue and skips the state writeback.
__global__ void scan_kernel(const float* __restrict__ wx,   // [nt*8][192][1024]
                            const float* __restrict__ wh,   // [8][192][1024]
                            const float* __restrict__ wcb,  // [8][128][1024]
                            const float* __restrict__ bih, const float* __restrict__ bhh,
                            const float* __restrict__ bch,
                            double* __restrict__ st, const float* __restrict__ c0,
                            float* __restrict__ outp, int t0, int nt) {
  const double DMI = 0.001 * 100.0;   // dt * tau_mem_inv
  const double DSI = 0.001 * 200.0;   // dt * tau_syn_inv
  int e = blockIdx.x * 256 + threadIdx.x;   // ((b*64+c)*1024)+hw
  int hw = e & 1023;
  int c = (e >> 10) & 63;
  int b = e >> 16;
  size_t o0 = ((size_t)b * 192 + c) * 1024 + hw;
  size_t w0 = ((size_t)b * 128 + c) * 1024 + hw;
  double cI = ((double)wh[o0] + (double)bhh[c]) + ((double)wcb[w0] + (double)bch[c]);
  double cF = ((double)wh[o0 + 64 * 1024] + (double)bhh[64 + c]) +
              ((double)wcb[w0 + 64 * 1024] + (double)bch[64 + c]);
  double cG = (double)wh[o0 + 128 * 1024] + (double)bhh[128 + c];
  double bI = (double)bih[c], bF = (double)bih[64 + c], bG = (double)bih[128 + c];

  double vi, ii, vf, fi, vg, gi, mi, mf, mg, mo;
  if (t0 == 0) {
    vi = ii = vf = fi = vg = gi = 0.0;
    mi = mf = mg = mo = -INFINITY;
  } else {
    vi = st[0 * NELEM + e]; ii = st[1 * NELEM + e];
    vf = st[2 * NELEM + e]; fi = st[3 * NELEM + e];
    vg = st[4 * NELEM + e]; gi = st[5 * NELEM + e];
    mi = st[6 * NELEM + e]; mf = st[7 * NELEM + e];
    mg = st[8 * NELEM + e]; mo = st[9 * NELEM + e];
  }
  for (int t = 0; t < nt; ++t) {
    const float* wp = wx + (size_t)(t * 8 + b) * (192 * 1024);
    double inpI = ((double)wp[(size_t)c * 1024 + hw] + bI) + cI;
    double inpF = ((double)wp[(size_t)(64 + c) * 1024 + hw] + bF) + cF;
    double inpG = ((double)wp[(size_t)(128 + c) * 1024 + hw] + bG) + cG;
    double vd = vi + DMI * (ii - vi);
    vi = (vd > 1.0) ? 0.0 : vd;
    ii = (ii - DSI * ii) + inpI;
    vd = vf + DMI * (fi - vf);
    vf = (vd > 1.0) ? 0.0 : vd;
    fi = (fi - DSI * fi) + inpF;
    vd = vg + DMI * (gi - vg);
    vg = (vd > 1.0) ? 0.0 : vd;
    gi = (gi - DSI * gi) + inpG;
    double vod = vg + DMI * (gi - vg);
    double vo = (vod > 1.0) ? 0.0 : vod;
    if (t0 + t >= 1) {
      mi = fmax(mi, vi); mf = fmax(mf, vf);
      mg = fmax(mg, vg); mo = fmax(mo, vo);
    }
  }
  if (t0 + nt >= SEQ) {
    double c1 = mf * (double)c0[e] + mi * mg;
    outp[e] = (float)(mo * tanh(c1));
    outp[NELEM + e] = (float)c1;
  } else {
    st[0 * NELEM + e] = vi; st[1 * NELEM + e] = ii;
    st[2 * NELEM + e] = vf; st[3 * NELEM + e] = fi;
    st[4 * NELEM + e] = vg; st[5 * NELEM + e] = gi;
    st[6 * NELEM + e] = mi; st[7 * NELEM + e] = mf;
    st[8 * NELEM + e] = mg; st[9 * NELEM + e] = mo;
  }
}

extern "C" void kernel_launch(void* const* d_in, const int* in_sizes, int n_in,
                              void* d_out, int out_size, void* d_ws, size_t ws_size,
                              hipStream_t stream) {
  const float* input = (const float*)d_in[0];
  const float* h0    = (const float*)d_in[1];
  const float* c0    = (const float*)d_in[2];
  const float* wih   = (const float*)d_in[3];
  const float* whh   = (const float*)d_in[4];
  const float* wch   = (const float*)d_in[5];
  const float* bih   = (const float*)d_in[6];
  const float* bhh   = (const float*)d_in[7];
  const float* bch   = (const float*)d_in[8];
  char* ws = (char*)d_ws;

  size_t off = 0;
  auto take = [&](size_t bytes) { size_t o = off; off += (bytes + 255) & ~(size_t)255; return o; };
  size_t oXp  = take((size_t)SEQ * 8 * PLANE);          // i8 spikes, 18.9 MB
  size_t oH1  = take((size_t)8 * PLANE * 2);
  size_t oH2  = take((size_t)8 * PLANE * 2);
  size_t oH3  = take((size_t)8 * PLANE * 2);
  size_t oC1  = take((size_t)8 * PLANE * 2);
  size_t oC2  = take((size_t)8 * PLANE * 2);
  size_t oC3  = take((size_t)8 * PLANE * 2);
  size_t oIq0 = take((size_t)9 * 192 * 64);             // i8 weight parts
  size_t oIq1 = take((size_t)9 * 192 * 64);
  size_t oIq2 = take((size_t)9 * 192 * 64);
  size_t oHh1 = take((size_t)9 * 192 * 64 * 2);
  size_t oHh2 = take((size_t)9 * 192 * 64 * 2);
  size_t oHh3 = take((size_t)9 * 192 * 64 * 2);
  size_t oCh1 = take((size_t)9 * 128 * 64 * 2);
  size_t oCh2 = take((size_t)9 * 128 * 64 * 2);
  size_t oCh3 = take((size_t)9 * 128 * 64 * 2);
  size_t oWh  = take((size_t)8 * 192 * 1024 * 4);
  size_t oWc  = take((size_t)8 * 128 * 1024 * 4);
  size_t oSt  = take((size_t)10 * NELEM * 8);
  size_t fixedEnd = off;
  const size_t chunkBytes = (size_t)8 * 192 * 1024 * 4;  // per-timestep wx bytes
  int chunk = 32;
  while (chunk > 1 && fixedEnd + (size_t)chunk * chunkBytes > ws_size) chunk >>= 1;
  size_t oWx = fixedEnd;

  s8* xp   = (s8*)(ws + oXp);
  u16* h1p = (u16*)(ws + oH1); u16* h2p = (u16*)(ws + oH2); u16* h3p = (u16*)(ws + oH3);
  u16* c1p = (u16*)(ws + oC1); u16* c2p = (u16*)(ws + oC2); u16* c3p = (u16*)(ws + oC3);
  s8* iq0  = (s8*)(ws + oIq0); s8* iq1 = (s8*)(ws + oIq1); s8* iq2 = (s8*)(ws + oIq2);
  u16* hh1 = (u16*)(ws + oHh1); u16* hh2 = (u16*)(ws + oHh2); u16* hh3 = (u16*)(ws + oHh3);
  u16* ch1 = (u16*)(ws + oCh1); u16* ch2 = (u16*)(ws + oCh2); u16* ch3 = (u16*)(ws + oCh3);
  float* whb = (float*)(ws + oWh);
  float* wcb = (float*)(ws + oWc);
  double* st = (double*)(ws + oSt);
  float* wxb = (float*)(ws + oWx);

  encode_kernel<<<2312, 256, 0, stream>>>(input, xp);
  prep_hc_kernel<<<2312, 256, 0, stream>>>(h0, c0, h1p, h2p, h3p, c1p, c2p, c3p);
  prep_w_kernel<<<1152, 256, 0, stream>>>(wih, whh, wch, iq0, iq1, iq2,
                                          hh1, hh2, hh3, ch1, ch2, ch3);

  conv1_kernel<<<dim3(5, 8, 8), 256, 0, stream>>>(
      h1p, h2p, h3p, c1p, c2p, c3p,
      hh1, hh2, hh3, ch1, ch2, ch3, whb, wcb);

  for (int t0 = 0; t0 < SEQ; t0 += chunk) {
    conv0_kernel<<<dim3(3, 4, 8 * chunk), 256, 0, stream>>>(
        xp + (size_t)t0 * 8 * PLANE, iq0, iq1, iq2, wxb);
    scan_kernel<<<2048, 256, 0, stream>>>(wxb, whb, wcb, bih, bhh, bch,
                                          st, c0, (float*)d_out, t0, chunk);
  }
}

// Round 6
// 235.024 us; speedup vs baseline: 1.9150x; 1.1940x over previous
//
#include <hip/hip_runtime.h>
#include <hip/hip_bf16.h>
#include <hip/hip_fp16.h>

typedef unsigned short u16;
typedef signed char s8;
typedef __attribute__((ext_vector_type(8))) short short8;
typedef __attribute__((ext_vector_type(4))) float f32x4;
typedef __attribute__((ext_vector_type(4))) int i32x4;

#define NELEM 524288          // 8*64*32*32
#define PADW 34
#define PLANE 73984           // 34*34*64 elements per padded image
#define SEQ 32

__device__ inline void split3(float v, u16& a, u16& b, u16& c) {
  __hip_bfloat16 h1 = __float2bfloat16(v);
  float r1 = v - __bfloat162float(h1);
  __hip_bfloat16 h2 = __float2bfloat16(r1);
  float r2 = r1 - __bfloat162float(h2);
  __hip_bfloat16 h3 = __float2bfloat16(r2);
  a = *reinterpret_cast<u16*>(&h1);
  b = *reinterpret_cast<u16*>(&h2);
  c = *reinterpret_cast<u16*>(&h3);
}

__device__ inline void gload16(const void* g, void* l) {
  typedef const __attribute__((address_space(1))) void* gp_t;
  typedef __attribute__((address_space(3))) void* lp_t;
  __builtin_amdgcn_global_load_lds((gp_t)g, (lp_t)l, 16, 0, 0);
}

// Constant-current LIF encoder in f64 over the PADDED plane (borders write 0).
// x(t) i8 exact 0/1, layout xp[t][b][py][px][c].
__global__ void encode_kernel(const float* __restrict__ input, s8* __restrict__ xp) {
  int e = blockIdx.x * 256 + threadIdx.x;   // (b*1156 + pp)*64 + c ; 8*1156*64 total
  int c = e & 63;
  int pp = (e >> 6) % 1156;
  int b = e / (1156 * 64);
  int py = pp / 34, px = pp - py * 34;
  size_t base = (size_t)b * PLANE + (size_t)pp * 64 + c;
  bool interior = (py >= 1 && py <= 32 && px >= 1 && px <= 32);
  const double DMI = 0.001 * 100.0;
  double inp = interior ? (double)input[(size_t)(((b << 6) + c) << 10) + (py - 1) * 32 + (px - 1)] : 0.0;
  double ve = 0.0;
  for (int t = 0; t < SEQ; ++t) {
    double v = ve + DMI * (inp - ve);
    bool x = interior && (v > 1.0);
    ve = x ? 0.0 : v;
    xp[(size_t)t * (8 * PLANE) + base] = x ? (s8)1 : (s8)0;
  }
}

// h0 / c0 -> padded channel-last, 3-way bf16 split; covers pad region with zeros.
__global__ void prep_hc_kernel(const float* __restrict__ h0, const float* __restrict__ c0,
                               u16* __restrict__ h1, u16* __restrict__ h2, u16* __restrict__ h3,
                               u16* __restrict__ c1, u16* __restrict__ c2, u16* __restrict__ c3) {
  int e = blockIdx.x * 256 + threadIdx.x;   // (b*1156 + pp)*64 + c
  int c = e & 63;
  int pp = (e >> 6) % 1156;
  int b = e / (1156 * 64);
  int py = pp / 34, px = pp - py * 34;
  size_t dst = (size_t)b * PLANE + (size_t)pp * 64 + c;
  bool interior = (py >= 1 && py <= 32 && px >= 1 && px <= 32);
  u16 a = 0, bb = 0, cc = 0, d = 0, ee = 0, ff = 0;
  if (interior) {
    size_t src = (size_t)(((b << 6) + c) << 10) + (py - 1) * 32 + (px - 1);
    split3(h0[src], a, bb, cc);
    split3(c0[src], d, ee, ff);
  }
  h1[dst] = a; h2[dst] = bb; h3[dst] = cc;
  c1[dst] = d; c2[dst] = ee; c3[dst] = ff;
}

// Weights: ih -> EXACT 24-bit fixed point, 3 signed-byte parts:
//   W24 = round(w*2^28) (|W24| < 2^23 since |w| <= 1/48), W24 = b2*2^16 + b1*2^8 + b0.
// hh/ch -> bf16 3-part. o-gate rows are dead.
__global__ void prep_w_kernel(const float* __restrict__ wih, const float* __restrict__ whh,
                              const float* __restrict__ wch,
                              s8* __restrict__ iq0, s8* __restrict__ iq1, s8* __restrict__ iq2,
                              u16* __restrict__ hh1, u16* __restrict__ hh2, u16* __restrict__ hh3,
                              u16* __restrict__ ch1, u16* __restrict__ ch2, u16* __restrict__ ch3) {
  int t = blockIdx.x * 256 + threadIdx.x;   // (tap*512 + row)*64 + c
  int c = t & 63;
  int row = (t >> 6) & 511;
  int tap = t >> 15;
  if (row < 192) {
    float v = wih[(size_t)((row << 6) + c) * 9 + tap];
    int Wi = (int)llrint((double)v * 268435456.0);
    int b0 = (Wi << 24) >> 24;
    int W1 = (Wi - b0) >> 8;
    int b1 = (W1 << 24) >> 24;
    int b2 = (W1 - b1) >> 8;
    size_t d = (size_t)(tap * 192 + row) * 64 + c;
    iq0[d] = (s8)b0; iq1[d] = (s8)b1; iq2[d] = (s8)b2;
  } else {
    const float* src; u16 *d1, *d2, *d3; int m, Mtot;
    if (row < 384) { src = whh; m = row - 192; Mtot = 192; d1 = hh1; d2 = hh2; d3 = hh3; }
    else           { src = wch; m = row - 384; Mtot = 128; d1 = ch1; d2 = ch2; d3 = ch3; }
    float v = src[(size_t)((m << 6) + c) * 9 + tap];
    u16 a, b, cc; split3(v, a, b, cc);
    size_t d = (size_t)(tap * Mtot + m) * 64 + c;
    d1[d] = a; d2[d] = b; d3[d] = cc;
  }
}

// wx conv, EXACT int8: spikes {0,1} x 3 byte-parts of 24-bit weights.
// mfma_i32_16x16x64_i8, K=64 = full channel depth -> one k-step per tap.
// Block 256 thr = 4 waves (2m x 2n). Tile BM=64, BN=128 px (4 rows).
// Wave: 32m x 64px -> acc 3x2x4 = 96 regs (occupancy fix vs round-5's 192).
// Per wave-tap: 10 ds_read_b128 vs 24 MFMA; LDS 37.7 KB -> 2-3 blocks/CU.
__global__ __launch_bounds__(256, 2) void conv0_kernel(
    const s8* __restrict__ X, const s8* __restrict__ W0p, const s8* __restrict__ W1p,
    const s8* __restrict__ W2p, float* __restrict__ out) {
  __shared__ uint4 ldsx4[816];     // 6 rows x 34 px x 64 B = 13056 B
  __shared__ uint4 ldsw4[1536];    // dbuf(2) x parts(3) x 4 KB = 24576 B
  char* ldsx = (char*)ldsx4;
  char* ldsw = (char*)ldsw4;

  const int tid = threadIdx.x;
  const int lane = tid & 63;
  const int wid = tid >> 6;
  const int mtile = blockIdx.x;     // 0..2
  const int rg = blockIdx.y;        // 0..7 (4 px-rows each)
  const int img = blockIdx.z;       // t*8 + b

  {  // stage X tile: linear LDS dest, inverse-swizzled source
    const char* src = (const char*)X + (size_t)img * PLANE + (size_t)rg * 4 * (PADW * 64);
    for (int q = tid; q < 816; q += 256) {
      int L = q << 4;
      gload16(src + (L ^ (((L >> 7) & 3) << 4)), ldsx + L);
    }
  }

  const s8* wps[3] = {W0p, W1p, W2p};
  const size_t wbase = (size_t)mtile * 64 * 64;
  auto stageW = [&](int tap, int buf) {
#pragma unroll
    for (int part = 0; part < 3; ++part) {
      const char* gsrc = (const char*)(wps[part] + (size_t)tap * 192 * 64 + wbase);
      int L = tid << 4;             // 256 granules of 16 B = 4 KB tile
      gload16(gsrc + (L ^ (((L >> 7) & 3) << 4)), ldsw + buf * 12288 + part * 4096 + L);
    }
  };
  stageW(0, 0);
  __syncthreads();

  i32x4 acc[3][2][4];   // [part][fm][fn] -- i32 exact
#pragma unroll
  for (int p = 0; p < 3; ++p)
#pragma unroll
    for (int i = 0; i < 2; ++i)
#pragma unroll
      for (int j = 0; j < 4; ++j)
#pragma unroll
        for (int k = 0; k < 4; ++k) acc[p][i][j][k] = 0;

  const int wm = wid >> 1, wn = wid & 1;
  const int kg = lane >> 4;         // k-group: 16 consecutive channels

  for (int tap = 0; tap < 9; ++tap) {
    if (tap < 8) stageW(tap + 1, (tap + 1) & 1);   // prefetch BEFORE compute
    char* wb = ldsw + (tap & 1) * 12288;
    const int kh = tap / 3, kw = tap - kh * 3;
    i32x4 bfr[4];
#pragma unroll
    for (int fn = 0; fn < 4; ++fn) {
      int p = wn * 64 + fn * 16 + (lane & 15);
      int r = p >> 5, w = p & 31;
      int pL = (r + kh) * PADW + (w + kw);
      int byte = (pL * 64 + kg * 16) ^ (((pL >> 1) & 3) << 4);
      bfr[fn] = *reinterpret_cast<const i32x4*>(ldsx + byte);
    }
#pragma unroll
    for (int part = 0; part < 3; ++part) {
      i32x4 af[2];
#pragma unroll
      for (int fm = 0; fm < 2; ++fm) {
        int m = wm * 32 + fm * 16 + (lane & 15);
        int byte = (m * 64 + kg * 16) ^ (((m >> 1) & 3) << 4);
        af[fm] = *reinterpret_cast<const i32x4*>(wb + part * 4096 + byte);
      }
      __builtin_amdgcn_s_setprio(1);
#pragma unroll
      for (int fm = 0; fm < 2; ++fm)
#pragma unroll
        for (int fn = 0; fn < 4; ++fn)
          acc[part][fm][fn] = __builtin_amdgcn_mfma_i32_16x16x64_i8(af[fm], bfr[fn], acc[part][fm][fn], 0, 0, 0);
      __builtin_amdgcn_s_setprio(0);
    }
    __syncthreads();
  }

  // D layout: col=lane&15 (pixel), row=(lane>>4)*4+reg (m). Exact recombine.
  size_t obase = (size_t)img * (192 * 1024);
  const double S0 = 1.0 / 268435456.0;   // 2^-28
#pragma unroll
  for (int fm = 0; fm < 2; ++fm)
#pragma unroll
    for (int fn = 0; fn < 4; ++fn) {
      int pcol = rg * 128 + wn * 64 + fn * 16 + (lane & 15);
      int mrow0 = mtile * 64 + wm * 32 + fm * 16 + (lane >> 4) * 4;
#pragma unroll
      for (int r2 = 0; r2 < 4; ++r2) {
        long long tot = ((long long)acc[2][fm][fn][r2] << 16) +
                        (long long)(acc[1][fm][fn][r2] * 256 + acc[0][fm][fn][r2]);
        out[obase + (size_t)(mrow0 + r2) * 1024 + pcol] = (float)((double)tot * S0);
      }
    }
}

// wh + wc conv merged: bf16 3-plane x 3-part, 6 cross terms. Block 256 thr.
// BM=64, BN=64 px (2 rows). LDS: X 52.2 KB + W single-buf 24.6 KB = 76.8 KB
// -> 2 blocks/CU (was 1). Grid 640 blocks. blockIdx.x: 0-2 wh, 3-4 wc.
__global__ __launch_bounds__(256) void conv1_kernel(
    const u16* __restrict__ Ah0, const u16* __restrict__ Ah1, const u16* __restrict__ Ah2,
    const u16* __restrict__ Ac0, const u16* __restrict__ Ac1, const u16* __restrict__ Ac2,
    const u16* __restrict__ Wh0, const u16* __restrict__ Wh1, const u16* __restrict__ Wh2,
    const u16* __restrict__ Wc0, const u16* __restrict__ Wc1, const u16* __restrict__ Wc2,
    float* __restrict__ outh, float* __restrict__ outc) {
  __shared__ uint4 ldsx4[3 * 1088];   // per plane: 4 rows x 34 px x 128 B
  __shared__ uint4 ldsw4[3 * 512];    // single buffer: 3 parts x 8 KB
  char* ldsx = (char*)ldsx4;
  char* ldsw = (char*)ldsw4;

  const int tid = threadIdx.x;
  const int lane = tid & 63;
  const int wid = tid >> 6;
  const bool isC = blockIdx.x >= 3;
  const int mtile = isC ? blockIdx.x - 3 : blockIdx.x;
  const int Mtot = isC ? 128 : 192;
  const int rg = blockIdx.y;          // 0..15 (2 px-rows each)
  const int img = blockIdx.z;
  const u16* aps[3] = {isC ? Ac0 : Ah0, isC ? Ac1 : Ah1, isC ? Ac2 : Ah2};
  const u16* wps[3] = {isC ? Wc0 : Wh0, isC ? Wc1 : Wh1, isC ? Wc2 : Wh2};
  float* out = isC ? outc : outh;

  {  // stage 3 X planes via global_load_lds (pre-swizzled source, linear dest)
    size_t abase = (size_t)img * PLANE + (size_t)rg * 2 * (PADW * 64);
#pragma unroll
    for (int pl = 0; pl < 3; ++pl) {
      const char* src = (const char*)(aps[pl] + abase);
      for (int q = tid; q < 1088; q += 256) {
        int L = q << 4;
        gload16(src + (L ^ (((L >> 7) & 7) << 4)), ldsx + pl * 17408 + L);
      }
    }
  }

  const size_t wrowbase = (size_t)mtile * 64 * 64;
  auto stageW = [&](int tap) {
#pragma unroll
    for (int part = 0; part < 3; ++part) {
      const char* gsrc = (const char*)(wps[part] + (size_t)tap * Mtot * 64 + wrowbase);
#pragma unroll
      for (int half = 0; half < 2; ++half) {
        int L = half * 4096 + tid * 16;
        gload16(gsrc + (L ^ (((L >> 7) & 7) << 4)), ldsw + part * 8192 + L);
      }
    }
  };

  f32x4 acc[2][2];
#pragma unroll
  for (int i = 0; i < 2; ++i)
#pragma unroll
    for (int j = 0; j < 2; ++j)
#pragma unroll
      for (int k = 0; k < 4; ++k) acc[i][j][k] = 0.f;

  const int wm = wid >> 1, wn = wid & 1;

  for (int tap = 0; tap < 9; ++tap) {
    if (tap) __syncthreads();       // everyone done with W[tap-1]
    stageW(tap);
    __syncthreads();                // W staged (drains vmcnt, incl. X on tap 0)
    const int kh = tap / 3, kw = tap - kh * 3;
#pragma unroll
    for (int khalf = 0; khalf < 2; ++khalf) {
      short8 af[3][2];
#pragma unroll
      for (int part = 0; part < 3; ++part)
#pragma unroll
        for (int fm = 0; fm < 2; ++fm) {
          int m = wm * 32 + fm * 16 + (lane & 15);
          int byte = (m * 128 + khalf * 64 + (lane >> 4) * 16) ^ ((m & 7) << 4);
          af[part][fm] = *reinterpret_cast<const short8*>(ldsw + part * 8192 + byte);
        }
#pragma unroll
      for (int pl = 0; pl < 3; ++pl) {
        short8 bfr[2];
#pragma unroll
        for (int fn = 0; fn < 2; ++fn) {
          int p = wn * 32 + fn * 16 + (lane & 15);
          int r = p >> 5, w = p & 31;
          int pL = (r + kh) * PADW + (w + kw);
          int byte = (pL * 128 + khalf * 64 + (lane >> 4) * 16) ^ ((pL & 7) << 4);
          bfr[fn] = *reinterpret_cast<const short8*>(ldsx + pl * 17408 + byte);
        }
        constexpr int npt[3] = {3, 2, 1};
        __builtin_amdgcn_s_setprio(1);
#pragma unroll
        for (int part = 0; part < 3; ++part) {
          if (part < npt[pl]) {
#pragma unroll
            for (int fm = 0; fm < 2; ++fm)
#pragma unroll
              for (int fn = 0; fn < 2; ++fn)
                acc[fm][fn] = __builtin_amdgcn_mfma_f32_16x16x32_bf16(af[part][fm], bfr[fn], acc[fm][fn], 0, 0, 0);
          }
        }
        __builtin_amdgcn_s_setprio(0);
      }
    }
  }

  size_t obase = (size_t)img * Mtot * 1024;
#pragma unroll
  for (int fm = 0; fm < 2; ++fm)
#pragma unroll
    for (int fn = 0; fn < 2; ++fn) {
      int pcol = rg * 64 + wn * 32 + fn * 16 + (lane & 15);
      int mrow0 = mtile * 64 + wm * 32 + fm * 16 + (lane >> 4) * 4;
#pragma unroll
      for (int r2 = 0; r2 < 4; ++r2)
        out[obase + (size_t)(mrow0 + r2) * 1024 + pcol] = acc[fm][fn][r2];
    }
}

// Sequential LIF gate scan. f64 states, f32 conv inputs. Last chunk fuses the
// c1/h1 epilogue and skips the state writeback.
__global__ void scan_kernel(const float* __restrict__ wx,   // [nt*8][192][1024]
                            const float* __restrict__ wh,   // [8][192][1024]
                            const float* __restrict__ wcb,  // [8][128][1024]
                            const float* __restrict__ bih, const float* __restrict__ bhh,
                            const float* __restrict__ bch,
                            double* __restrict__ st, const float* __restrict__ c0,
                            float* __restrict__ outp, int t0, int nt) {
  const double DMI = 0.001 * 100.0;   // dt * tau_mem_inv
  const double DSI = 0.001 * 200.0;   // dt * tau_syn_inv
  int e = blockIdx.x * 256 + threadIdx.x;   // ((b*64+c)*1024)+hw
  int hw = e & 1023;
  int c = (e >> 10) & 63;
  int b = e >> 16;
  size_t o0 = ((size_t)b * 192 + c) * 1024 + hw;
  size_t w0 = ((size_t)b * 128 + c) * 1024 + hw;
  double cI = ((double)wh[o0] + (double)bhh[c]) + ((double)wcb[w0] + (double)bch[c]);
  double cF = ((double)wh[o0 + 64 * 1024] + (double)bhh[64 + c]) +
              ((double)wcb[w0 + 64 * 1024] + (double)bch[64 + c]);
  double cG = (double)wh[o0 + 128 * 1024] + (double)bhh[128 + c];
  double bI = (double)bih[c], bF = (double)bih[64 + c], bG = (double)bih[128 + c];

  double vi, ii, vf, fi, vg, gi, mi, mf, mg, mo;
  if (t0 == 0) {
    vi = ii = vf = fi = vg = gi = 0.0;
    mi = mf = mg = mo = -INFINITY;
  } else {
    vi = st[0 * NELEM + e]; ii = st[1 * NELEM + e];
    vf = st[2 * NELEM + e]; fi = st[3 * NELEM + e];
    vg = st[4 * NELEM + e]; gi = st[5 * NELEM + e];
    mi = st[6 * NELEM + e]; mf = st[7 * NELEM + e];
    mg = st[8 * NELEM + e]; mo = st[9 * NELEM + e];
  }
  for (int t = 0; t < nt; ++t) {
    const float* wp = wx + (size_t)(t * 8 + b) * (192 * 1024);
    double inpI = ((double)wp[(size_t)c * 1024 + hw] + bI) + cI;
    double inpF = ((double)wp[(size_t)(64 + c) * 1024 + hw] + bF) + cF;
    double inpG = ((double)wp[(size_t)(128 + c) * 1024 + hw] + bG) + cG;
    double vd = vi + DMI * (ii - vi);
    vi = (vd > 1.0) ? 0.0 : vd;
    ii = (ii - DSI * ii) + inpI;
    vd = vf + DMI * (fi - vf);
    vf = (vd > 1.0) ? 0.0 : vd;
    fi = (fi - DSI * fi) + inpF;
    vd = vg + DMI * (gi - vg);
    vg = (vd > 1.0) ? 0.0 : vd;
    gi = (gi - DSI * gi) + inpG;
    double vod = vg + DMI * (gi - vg);
    double vo = (vod > 1.0) ? 0.0 : vod;
    if (t0 + t >= 1) {
      mi = fmax(mi, vi); mf = fmax(mf, vf);
      mg = fmax(mg, vg); mo = fmax(mo, vo);
    }
  }
  if (t0 + nt >= SEQ) {
    double c1 = mf * (double)c0[e] + mi * mg;
    outp[e] = (float)(mo * tanh(c1));
    outp[NELEM + e] = (float)c1;
  } else {
    st[0 * NELEM + e] = vi; st[1 * NELEM + e] = ii;
    st[2 * NELEM + e] = vf; st[3 * NELEM + e] = fi;
    st[4 * NELEM + e] = vg; st[5 * NELEM + e] = gi;
    st[6 * NELEM + e] = mi; st[7 * NELEM + e] = mf;
    st[8 * NELEM + e] = mg; st[9 * NELEM + e] = mo;
  }
}

extern "C" void kernel_launch(void* const* d_in, const int* in_sizes, int n_in,
                              void* d_out, int out_size, void* d_ws, size_t ws_size,
                              hipStream_t stream) {
  const float* input = (const float*)d_in[0];
  const float* h0    = (const float*)d_in[1];
  const float* c0    = (const float*)d_in[2];
  const float* wih   = (const float*)d_in[3];
  const float* whh   = (const float*)d_in[4];
  const float* wch   = (const float*)d_in[5];
  const float* bih   = (const float*)d_in[6];
  const float* bhh   = (const float*)d_in[7];
  const float* bch   = (const float*)d_in[8];
  char* ws = (char*)d_ws;

  size_t off = 0;
  auto take = [&](size_t bytes) { size_t o = off; off += (bytes + 255) & ~(size_t)255; return o; };
  size_t oXp  = take((size_t)SEQ * 8 * PLANE);          // i8 spikes, 18.9 MB
  size_t oH1  = take((size_t)8 * PLANE * 2);
  size_t oH2  = take((size_t)8 * PLANE * 2);
  size_t oH3  = take((size_t)8 * PLANE * 2);
  size_t oC1  = take((size_t)8 * PLANE * 2);
  size_t oC2  = take((size_t)8 * PLANE * 2);
  size_t oC3  = take((size_t)8 * PLANE * 2);
  size_t oIq0 = take((size_t)9 * 192 * 64);             // i8 weight parts
  size_t oIq1 = take((size_t)9 * 192 * 64);
  size_t oIq2 = take((size_t)9 * 192 * 64);
  size_t oHh1 = take((size_t)9 * 192 * 64 * 2);
  size_t oHh2 = take((size_t)9 * 192 * 64 * 2);
  size_t oHh3 = take((size_t)9 * 192 * 64 * 2);
  size_t oCh1 = take((size_t)9 * 128 * 64 * 2);
  size_t oCh2 = take((size_t)9 * 128 * 64 * 2);
  size_t oCh3 = take((size_t)9 * 128 * 64 * 2);
  size_t oWh  = take((size_t)8 * 192 * 1024 * 4);
  size_t oWc  = take((size_t)8 * 128 * 1024 * 4);
  size_t fixedEnd = off;

  const size_t chunkBytes = (size_t)8 * 192 * 1024 * 4;  // per-timestep wx bytes
  int chunk;
  size_t oWx, oSt;
  if (fixedEnd + 32 * chunkBytes <= ws_size) {
    chunk = 32;                       // single conv0+scan pass, no st round-trip
    oWx = fixedEnd;
    oSt = fixedEnd;                   // unused (scan never touches st at chunk 32)
  } else {
    oSt = take((size_t)10 * NELEM * 8);
    size_t fe2 = off;
    chunk = 16;
    while (chunk > 1 && fe2 + (size_t)chunk * chunkBytes > ws_size) chunk >>= 1;
    oWx = fe2;
  }

  s8* xp   = (s8*)(ws + oXp);
  u16* h1p = (u16*)(ws + oH1); u16* h2p = (u16*)(ws + oH2); u16* h3p = (u16*)(ws + oH3);
  u16* c1p = (u16*)(ws + oC1); u16* c2p = (u16*)(ws + oC2); u16* c3p = (u16*)(ws + oC3);
  s8* iq0  = (s8*)(ws + oIq0); s8* iq1 = (s8*)(ws + oIq1); s8* iq2 = (s8*)(ws + oIq2);
  u16* hh1 = (u16*)(ws + oHh1); u16* hh2 = (u16*)(ws + oHh2); u16* hh3 = (u16*)(ws + oHh3);
  u16* ch1 = (u16*)(ws + oCh1); u16* ch2 = (u16*)(ws + oCh2); u16* ch3 = (u16*)(ws + oCh3);
  float* whb = (float*)(ws + oWh);
  float* wcb = (float*)(ws + oWc);
  double* st = (double*)(ws + oSt);
  float* wxb = (float*)(ws + oWx);

  encode_kernel<<<2312, 256, 0, stream>>>(input, xp);
  prep_hc_kernel<<<2312, 256, 0, stream>>>(h0, c0, h1p, h2p, h3p, c1p, c2p, c3p);
  prep_w_kernel<<<1152, 256, 0, stream>>>(wih, whh, wch, iq0, iq1, iq2,
                                          hh1, hh2, hh3, ch1, ch2, ch3);

  conv1_kernel<<<dim3(5, 16, 8), 256, 0, stream>>>(
      h1p, h2p, h3p, c1p, c2p, c3p,
      hh1, hh2, hh3, ch1, ch2, ch3, whb, wcb);

  for (int t0 = 0; t0 < SEQ; t0 += chunk) {
    conv0_kernel<<<dim3(3, 8, 8 * chunk), 256, 0, stream>>>(
        xp + (size_t)t0 * 8 * PLANE, iq0, iq1, iq2, wxb);
    scan_kernel<<<2048, 256, 0, stream>>>(wxb, whb, wcb, bih, bhh, bch,
                                          st, c0, (float*)d_out, t0, chunk);
  }
}